// Round 2
// baseline (1413.277 us; speedup 1.0000x reference)
//
#include <hip/hip_runtime.h>
#include <hip/hip_bf16.h>

typedef __attribute__((ext_vector_type(8))) __bf16 bf16x8;
typedef __attribute__((ext_vector_type(4))) float f32x4;

#define ACT_NONE 0
#define ACT_RELU 1
#define ACT_GELU 2
#define ACT_TANH 3
#define OUT_F32 0
#define OUT_BF16 1
#define OUT_ADD 2

// ---------------- async global->LDS, 16B per lane (lane writes lds_base + lane*16) ----------------
__device__ __forceinline__ void gll16(const void* g, void* l) {
  __builtin_amdgcn_global_load_lds(
      reinterpret_cast<const __attribute__((address_space(1))) unsigned int*>(
          reinterpret_cast<unsigned long long>(g)),
      reinterpret_cast<__attribute__((address_space(3))) unsigned int*>(
          reinterpret_cast<unsigned long long>(l)),
      16, 0, 0);
}

// ---------------- bijective XCD-chunked swizzle (m204): keep adjacent blocks on one XCD L2 ----------
__device__ __forceinline__ int xcd_swz(int bid, int n) {
  const int q = n >> 3, r = n & 7, x = bid & 7, o = bid >> 3;
  return (x < r ? x * (q + 1) : r * (q + 1) + (x - r) * q) + o;
}

// ---------------- implicit-GEMM A addressing ----------------
// MODE 0: plain row-major A[M][K]
// MODE 1: conv1 im2col: input (1920,84,84,4) f32, 8x8 s4 -> k=ky*32+(kx*4+ci)
// MODE 2: conv2 im2col: input (1920,20,20,32), 4x4 s2 -> k=(ky*4+kx)*32+ci
// MODE 3: conv3 im2col: input (1920,9,9,64),  3x3 s1 -> k=(ky*3+kx)*64+ci
template<int MODE, int K>
__device__ __forceinline__ size_t a_rowbase(int m) {
  if constexpr (MODE == 0) {
    return (size_t)m * K;
  } else if constexpr (MODE == 1) {
    int img = m / 400; int p = m - img * 400; int oy = p / 20; int ox = p - oy * 20;
    return (size_t)img * 28224 + oy * 1344 + ox * 16;
  } else if constexpr (MODE == 2) {
    int img = m / 81; int p = m - img * 81; int oy = p / 9; int ox = p - oy * 9;
    return (size_t)img * 12800 + oy * 1280 + ox * 64;
  } else {
    int img = m / 49; int p = m - img * 49; int oy = p / 7; int ox = p - oy * 7;
    return (size_t)img * 5184 + oy * 576 + ox * 64;
  }
}
// logical k -> physical element offset within an im2col row window (full-k closed form;
// 8-element chunks never straddle a contiguous physical run in any mode)
template<int MODE>
__device__ __forceinline__ int kphys(int k) {
  if constexpr (MODE == 0) return k;
  else if constexpr (MODE == 2) return (k >> 7) * 640 + ((k >> 5) & 3) * 32 + (k & 31);
  else return k + (k / 192) * 384;  // MODE 3: ky*576 + (k - ky*192)
}

__device__ __forceinline__ bf16x8 ld8f(const float* f) {
  float4 a = *(const float4*)f;
  float4 b = *(const float4*)(f + 4);
  bf16x8 r;
  r[0] = (__bf16)a.x; r[1] = (__bf16)a.y; r[2] = (__bf16)a.z; r[3] = (__bf16)a.w;
  r[4] = (__bf16)b.x; r[5] = (__bf16)b.y; r[6] = (__bf16)b.z; r[7] = (__bf16)b.w;
  return r;
}

__device__ __forceinline__ float act_apply(float v, int ACT) {
  if (ACT == ACT_RELU) return fmaxf(v, 0.f);
  if (ACT == ACT_GELU) return 0.5f * v * (1.f + erff(v * 0.70710678118f));
  if (ACT == ACT_TANH) return tanhf(v);
  return v;
}

// ---------------- generic MFMA GEMM:  C[M][N] = act(A * BT^T + bias) ----------------
// BK=64 (half the barrier drains of BK=32), XOR-swizzled LDS:
//   physical 16B chunk c at row r holds logical chunk c ^ (r&7); global_load_lds writes
//   linearly (lane*16) while each lane pre-fetches its swizzled logical chunk (per-lane
//   global address), reads apply the same involution -> 2-way max bank aliasing (free).
// A bf16 addressed per MODE; BT bf16 [N][K] row-major. 4 waves WM x WN.
// Requires: TM%32==0, TN%32==0, SM%16==0, SN%16==0, K%64==0, all dims exact.
template<int MODE, int TM, int TN, int WM, int WN, int K, int ACT, int OUTM, int LDC, int SWZ>
__global__ __launch_bounds__(256) void gemm_k(const __bf16* __restrict__ A,
                                              const __bf16* __restrict__ BT,
                                              const float* __restrict__ bias,
                                              void* __restrict__ C) {
  constexpr int SM = TM / WM, SN = TN / WN;
  constexpr int AM = SM / 16, AN = SN / 16;
  constexpr int TA = TM / 32, TB = TN / 32;  // gll16 per wave (each covers 8 rows x 64 cols)
  __shared__ __align__(16) __bf16 As[TM * 64];
  __shared__ __align__(16) __bf16 Bs[TN * 64];
  const int tid = threadIdx.x;
  const int wave = tid >> 6, lane = tid & 63;
  const int quad = lane >> 4, l16 = lane & 15;
  const int wr = wave % WM, wc = wave / WM;
  const int bm = SWZ ? xcd_swz(blockIdx.x, gridDim.x) : blockIdx.x;
  const int m0 = bm * TM, n0 = blockIdx.y * TN;
  const int srow = lane >> 3;              // staging: row within the 8-row group
  const int schk = (lane & 7) ^ srow;      // pre-swizzled logical chunk (XOR involution)

  const __bf16* ga[TA];
  const __bf16* gb[TB];
#pragma unroll
  for (int t = 0; t < TA; ++t) {
    const int row = m0 + (wave + 4 * t) * 8 + srow;
    ga[t] = A + a_rowbase<MODE, K>(row) + (MODE == 0 ? schk * 8 : 0);
  }
#pragma unroll
  for (int t = 0; t < TB; ++t)
    gb[t] = BT + (size_t)(n0 + (wave + 4 * t) * 8 + srow) * K + schk * 8;

  f32x4 acc[AM][AN] = {};
  for (int kt = 0; kt < K / 64; ++kt) {
    const int kb = kt * 64;
    int ka;
    if constexpr (MODE == 0) ka = kb;
    else ka = kphys<MODE>(kb + schk * 8);
    __syncthreads();
#pragma unroll
    for (int t = 0; t < TA; ++t)
      gll16(ga[t] + ka, &As[(wave + 4 * t) * 8 * 64]);
#pragma unroll
    for (int t = 0; t < TB; ++t)
      gll16(gb[t] + kb, &Bs[(wave + 4 * t) * 8 * 64]);
    __syncthreads();
#pragma unroll
    for (int ks = 0; ks < 2; ++ks) {
      const int xa = (((ks * 4 + quad) ^ (l16 & 7)) * 8);  // swizzled chunk offset (elems)
      bf16x8 af[AM], bq[AN];
#pragma unroll
      for (int mt = 0; mt < AM; ++mt)
        af[mt] = *(const bf16x8*)&As[(wr * SM + mt * 16 + l16) * 64 + xa];
#pragma unroll
      for (int nt = 0; nt < AN; ++nt)
        bq[nt] = *(const bf16x8*)&Bs[(wc * SN + nt * 16 + l16) * 64 + xa];
#pragma unroll
      for (int mt = 0; mt < AM; ++mt)
#pragma unroll
        for (int nt = 0; nt < AN; ++nt)
          acc[mt][nt] = __builtin_amdgcn_mfma_f32_16x16x32_bf16(af[mt], bq[nt], acc[mt][nt], 0, 0, 0);
    }
  }

  // epilogue: C/D layout col=lane&15, row=quad*4+reg
#pragma unroll
  for (int nt = 0; nt < AN; ++nt) {
    const int col = n0 + wc * SN + nt * 16 + l16;
    const float bvl = bias[col];
#pragma unroll
    for (int mt = 0; mt < AM; ++mt) {
#pragma unroll
      for (int r = 0; r < 4; ++r) {
        const int row = m0 + wr * SM + mt * 16 + quad * 4 + r;
        float v = act_apply(acc[mt][nt][r] + bvl, ACT);
        const size_t off = (size_t)row * LDC + col;
        if constexpr (OUTM == OUT_F32) ((float*)C)[off] = v;
        else if constexpr (OUTM == OUT_BF16) ((__bf16*)C)[off] = (__bf16)v;
        else ((float*)C)[off] += v;
      }
    }
  }
}

// ---------------- conv1: f32 A (im2col MODE 1), 128x32 tile, K=256 ----------------
__global__ __launch_bounds__(256) void conv1_k(const float* __restrict__ A,
                                               const __bf16* __restrict__ BT,
                                               const float* __restrict__ bias,
                                               __bf16* __restrict__ C) {
  __shared__ __align__(16) __bf16 As[128 * 32];
  __shared__ __align__(16) __bf16 Bs[32 * 32];
  const int tid = threadIdx.x;
  const int wave = tid >> 6, lane = tid & 63;
  const int quad = lane >> 4, l16 = lane & 15;
  const int m0 = xcd_swz(blockIdx.x, gridDim.x) * 128;  // XCD-chunked: window overlap stays in L2
  const int lrow = lane >> 2, lkc = lane & 3;
  const int r0 = tid >> 2, k0o = (tid & 3) * 8;  // A staging: rows r0, r0+64
  const int r1 = r0 + 64;
  const size_t ar0 = a_rowbase<1, 256>(m0 + r0);
  const size_t ar1 = a_rowbase<1, 256>(m0 + r1);
  const __bf16* gB = BT + (size_t)(wave * 16 + lrow) * 256 + lkc * 8;  // used by waves 0,1

  f32x4 acc[2][2] = {};
  bf16x8 a0 = ld8f(A + ar0 + k0o);
  bf16x8 a1 = ld8f(A + ar1 + k0o);
  for (int kt = 0; kt < 8; ++kt) {
    const int kb = kt * 32;
    __syncthreads();
    if (wave < 2) gll16(gB + kb, &Bs[wave * 16 * 32]);
    *(bf16x8*)&As[r0 * 32 + k0o] = a0;
    *(bf16x8*)&As[r1 * 32 + k0o] = a1;
    __syncthreads();
    if (kt < 7) {
      const int fa = (kt + 1) * 336;  // f32 offset for k-block kt+1 (ky stride 336 floats)
      a0 = ld8f(A + ar0 + fa + k0o);
      a1 = ld8f(A + ar1 + fa + k0o);
    }
    bf16x8 af[2], bf[2];
#pragma unroll
    for (int mt = 0; mt < 2; ++mt)
      af[mt] = *(const bf16x8*)&As[(wave * 32 + mt * 16 + l16) * 32 + quad * 8];
#pragma unroll
    for (int nt = 0; nt < 2; ++nt)
      bf[nt] = *(const bf16x8*)&Bs[(nt * 16 + l16) * 32 + quad * 8];
#pragma unroll
    for (int mt = 0; mt < 2; ++mt)
#pragma unroll
      for (int nt = 0; nt < 2; ++nt)
        acc[mt][nt] = __builtin_amdgcn_mfma_f32_16x16x32_bf16(af[mt], bf[nt], acc[mt][nt], 0, 0, 0);
  }
#pragma unroll
  for (int nt = 0; nt < 2; ++nt) {
    const int col = nt * 16 + l16;
    const float bvl = bias[col];
#pragma unroll
    for (int mt = 0; mt < 2; ++mt) {
#pragma unroll
      for (int r = 0; r < 4; ++r) {
        const int row = m0 + wave * 32 + mt * 16 + quad * 4 + r;
        C[(size_t)row * 32 + col] = (__bf16)fmaxf(acc[mt][nt][r] + bvl, 0.f);
      }
    }
  }
}

// ---------------- transpose + pad (+scale): dst[Cpad][R] = src[R][C]^T, f32 src ----------------
template<typename TO>
__global__ void transpose_pad(const float* __restrict__ src, TO* __restrict__ dst,
                              int R, int C, int Cpad, long long sz, long long dz, float scale) {
  src += blockIdx.z * sz; dst += blockIdx.z * dz;
  __shared__ float t[32][33];
  const int tx = threadIdx.x, ty = threadIdx.y;
  const int r0 = blockIdx.x * 32, c0 = blockIdx.y * 32;
  for (int i = ty; i < 32; i += 8) {
    int r = r0 + i, c = c0 + tx;
    t[i][tx] = (r < R && c < C) ? src[(size_t)r * C + c] : 0.f;
  }
  __syncthreads();
  for (int i = ty; i < 32; i += 8) {
    int c = c0 + i, r = r0 + tx;
    if (c < Cpad && r < R)
      dst[(size_t)c * R + r] = (c < C) ? (TO)(t[tx][i] * scale) : (TO)0.f;
  }
}

// ---------------- merged K/Q/V weight transpose: 3 launches -> 1; all 512x512, no padding ------
__global__ void transpose_qkv(const float* __restrict__ Wk_, const float* __restrict__ Wq_,
                              const float* __restrict__ Wv_, __bf16* __restrict__ dst) {
  const int z = blockIdx.z, which = z / 6, i = z - which * 6;  // grid z = 18
  const float* src = (which == 0 ? Wk_ : which == 1 ? Wq_ : Wv_) + (size_t)i * 512 * 512;
  __bf16* d = dst + (size_t)i * 1536 * 512 + (size_t)which * 512 * 512;
  __shared__ float t[32][33];
  const int tx = threadIdx.x, ty = threadIdx.y;
  const int r0 = blockIdx.x * 32, c0 = blockIdx.y * 32;
  for (int j = ty; j < 32; j += 8)
    t[j][tx] = src[(size_t)(r0 + j) * 512 + c0 + tx];
  __syncthreads();
  for (int j = ty; j < 32; j += 8)
    d[(size_t)(c0 + j) * 512 + r0 + tx] = (__bf16)t[tx][j];
}

__global__ void biascat_k(const float* bk, const float* bq, const float* bv, float* dst) {
  const int i = blockIdx.x;
  for (int d = threadIdx.x; d < 512; d += 256) {
    dst[i * 1536 + d] = bk[i * 512 + d];
    dst[i * 1536 + 512 + d] = bq[i * 512 + d];
    dst[i * 1536 + 1024 + d] = bv[i * 512 + d];
  }
}

// ---------------- token embedding: x = interleave(rtg_e, st_e, a_e) + pos ----------------
__global__ void embed_k(const float* __restrict__ rtgs, const int* __restrict__ actions,
                        const int* __restrict__ timesteps, const float* __restrict__ W_rtg,
                        const float* __restrict__ b_rtg, const float* __restrict__ emb_a,
                        const float* __restrict__ abs_pos, const float* __restrict__ rel_pos,
                        const float* __restrict__ ste, float* __restrict__ x) {
  const int idx = blockIdx.x * 256 + threadIdx.x;  // 64*90*512 total
  const int d = idx & 511; const int rb = idx >> 9;
  const int b = rb / 90, t = rb - b * 90;
  const int l = t / 3, r = t - l * 3;
  const float pos = rel_pos[t * 512 + d] + abs_pos[(size_t)timesteps[b] * 512 + d];
  float tok;
  if (r == 0) tok = tanhf(rtgs[b * 30 + l] * W_rtg[d] + b_rtg[d]);
  else if (r == 1) tok = ste[(size_t)(b * 30 + l) * 512 + d];
  else tok = tanhf(emb_a[actions[b * 30 + l] * 512 + d]);
  x[idx] = tok + pos;
}

// ---------------- layernorm: h_bf16 = LN(x_f32) * g + b, one wave per row ----------------
__global__ __launch_bounds__(256) void ln_k(const float* __restrict__ x, const float* __restrict__ g,
                                            const float* __restrict__ bb, __bf16* __restrict__ h) {
  const int row = blockIdx.x * 4 + (threadIdx.x >> 6);
  const int lane = threadIdx.x & 63;
  const float* xr = x + (size_t)row * 512;
  float4 a = *(const float4*)&xr[lane * 8];
  float4 c = *(const float4*)&xr[lane * 8 + 4];
  float vv[8] = {a.x, a.y, a.z, a.w, c.x, c.y, c.z, c.w};
  float s = 0.f, q = 0.f;
#pragma unroll
  for (int j = 0; j < 8; ++j) { s += vv[j]; q += vv[j] * vv[j]; }
  for (int o = 32; o; o >>= 1) { s += __shfl_xor(s, o); q += __shfl_xor(q, o); }
  const float mean = s * (1.f / 512.f);
  const float var = q * (1.f / 512.f) - mean * mean;
  const float rstd = rsqrtf(var + 1e-3f);
  float4 g1 = *(const float4*)&g[lane * 8];
  float4 g2 = *(const float4*)&g[lane * 8 + 4];
  float4 b1 = *(const float4*)&bb[lane * 8];
  float4 b2 = *(const float4*)&bb[lane * 8 + 4];
  float gg[8] = {g1.x, g1.y, g1.z, g1.w, g2.x, g2.y, g2.z, g2.w};
  float bbv[8] = {b1.x, b1.y, b1.z, b1.w, b2.x, b2.y, b2.z, b2.w};
  bf16x8 ov;
#pragma unroll
  for (int j = 0; j < 8; ++j)
    ov[j] = (__bf16)((vv[j] - mean) * rstd * gg[j] + bbv[j]);
  *(bf16x8*)&h[(size_t)row * 512 + lane * 8] = ov;
}

// ---------------- fused attention per (b,h): s=K@Q^T/8 masked, softmax, o=W@V, x += o ----------
// V global loads issued at kernel entry (registers), LDS-written only at the barrier before PV:
// hides the V HBM latency under scores+softmax instead of serializing it after softmax.
__global__ __launch_bounds__(256) void attn_k(const __bf16* __restrict__ qkv, float* __restrict__ x) {
  __shared__ __align__(16) char smem[64512];
  __bf16* kS = (__bf16*)smem;              // [96][72]  13824B
  __bf16* qS = (__bf16*)(smem + 13824);    // [96][72]  13824B
  __bf16* wS = (__bf16*)smem;              // [96][104] 19968B (reuses k/q after scores)
  float* sS = (float*)(smem + 27648);      // [96][96]  36864B
  __bf16* vT = (__bf16*)(smem + 27648);    // [64][104] 13312B (reuses sS after softmax)

  const int tid = threadIdx.x;
  const int b = blockIdx.x >> 3, h = blockIdx.x & 7;
  const int wave = tid >> 6, lane = tid & 63, quad = lane >> 4, l16 = lane & 15;
  const size_t rowbase = (size_t)b * 90 * 1536 + h * 64;

  // phase 0: issue V loads into registers (consumed in phase 4; latency hidden under phases 1-3)
  bf16x8 vreg[3];
#pragma unroll
  for (int it = 0; it < 3; ++it) {
    const int c = tid + it * 256, t = c >> 3, d8 = (c & 7) * 8;
#pragma unroll
    for (int j = 0; j < 8; ++j) vreg[it][j] = (__bf16)0.f;
    if (t < 90) vreg[it] = *(const bf16x8*)(qkv + rowbase + (size_t)t * 1536 + 1024 + d8);
  }

  // phase 1: load K, Q tiles (zero-pad rows 90..95)
  for (int c = tid; c < 768; c += 256) {
    const int t = c >> 3, d8 = (c & 7) * 8;
    bf16x8 kv, qv;
#pragma unroll
    for (int j = 0; j < 8; ++j) { kv[j] = (__bf16)0.f; qv[j] = (__bf16)0.f; }
    if (t < 90) {
      const __bf16* src = qkv + rowbase + (size_t)t * 1536 + d8;
      kv = *(const bf16x8*)src;
      qv = *(const bf16x8*)(src + 512);
    }
    *(bf16x8*)&kS[t * 72 + d8] = kv;
    *(bf16x8*)&qS[t * 72 + d8] = qv;
  }
  __syncthreads();

  // phase 2: s[i][j] = sum_d k[i,d] q[j,d] / 8, causal mask j<=i
  for (int tt = wave; tt < 36; tt += 4) {
    const int it = tt / 6, jt = tt - it * 6;
    f32x4 acc = {0.f, 0.f, 0.f, 0.f};
#pragma unroll
    for (int ks = 0; ks < 2; ++ks) {
      bf16x8 af = *(const bf16x8*)&kS[(it * 16 + l16) * 72 + ks * 32 + quad * 8];
      bf16x8 bq = *(const bf16x8*)&qS[(jt * 16 + l16) * 72 + ks * 32 + quad * 8];
      acc = __builtin_amdgcn_mfma_f32_16x16x32_bf16(af, bq, acc, 0, 0, 0);
    }
    const int col = jt * 16 + l16;
#pragma unroll
    for (int r = 0; r < 4; ++r) {
      const int row = it * 16 + quad * 4 + r;
      sS[row * 96 + col] = (col <= row && col < 90) ? acc[r] * 0.125f : -1e30f;
    }
  }
  __syncthreads();

  // phase 3: row softmax -> wS (bf16)
  for (int row = wave; row < 96; row += 4) {
    const float e0 = sS[row * 96 + lane];
    const float e1 = (lane < 32) ? sS[row * 96 + 64 + lane] : -1e30f;
    float m = fmaxf(e0, e1);
    for (int o = 32; o; o >>= 1) m = fmaxf(m, __shfl_xor(m, o));
    const float p0 = __expf(e0 - m);
    const float p1 = (lane < 32) ? __expf(e1 - m) : 0.f;
    float s = p0 + p1;
    for (int o = 32; o; o >>= 1) s += __shfl_xor(s, o);
    const float inv = 1.f / s;
    wS[row * 104 + lane] = (__bf16)(p0 * inv);
    if (lane < 32) wS[row * 104 + 64 + lane] = (__bf16)(p1 * inv);
  }
  __syncthreads();

  // phase 4: write preloaded V transposed into vT[d][j] (zero-pad cols 90..95)
#pragma unroll
  for (int it = 0; it < 3; ++it) {
    const int c = tid + it * 256, t = c >> 3, d8 = (c & 7) * 8;
#pragma unroll
    for (int j = 0; j < 8; ++j) vT[(d8 + j) * 104 + t] = vreg[it][j];
  }
  __syncthreads();

  // phase 5: o[i][d] = sum_j w[i,j] v[j,d]; x[b, i, h*64+d] += o
  for (int tt = wave; tt < 24; tt += 4) {
    const int it = tt >> 2, dt = tt & 3;
    f32x4 acc = {0.f, 0.f, 0.f, 0.f};
#pragma unroll
    for (int ks = 0; ks < 3; ++ks) {
      bf16x8 aw = *(const bf16x8*)&wS[(it * 16 + l16) * 104 + ks * 32 + quad * 8];
      bf16x8 bv = *(const bf16x8*)&vT[(dt * 16 + l16) * 104 + ks * 32 + quad * 8];
      acc = __builtin_amdgcn_mfma_f32_16x16x32_bf16(aw, bv, acc, 0, 0, 0);
    }
    const int d = dt * 16 + l16;
#pragma unroll
    for (int r = 0; r < 4; ++r) {
      const int i = it * 16 + quad * 4 + r;
      if (i < 90) {
        float* p = x + (size_t)(b * 90 + i) * 512 + h * 64 + d;
        *p += acc[r];
      }
    }
  }
}

// ---------------- fused final LN + head (state tokens only), 1 wave per output row ----------------
__global__ __launch_bounds__(64) void head_k(const float* __restrict__ x, const float* __restrict__ g,
                                             const float* __restrict__ bb, const float* __restrict__ whT,
                                             float* __restrict__ out) {
  const int m = blockIdx.x;  // 0..1919 = b*30+l
  const int b = m / 30, l = m - b * 30;
  const float* xr = x + (size_t)(b * 90 + 3 * l + 1) * 512;
  const int lane = threadIdx.x;
  float4 a = *(const float4*)&xr[lane * 8];
  float4 c = *(const float4*)&xr[lane * 8 + 4];
  float vv[8] = {a.x, a.y, a.z, a.w, c.x, c.y, c.z, c.w};
  float s = 0.f, q = 0.f;
#pragma unroll
  for (int j = 0; j < 8; ++j) { s += vv[j]; q += vv[j] * vv[j]; }
  for (int o = 32; o; o >>= 1) { s += __shfl_xor(s, o); q += __shfl_xor(q, o); }
  const float mean = s * (1.f / 512.f);
  const float var = q * (1.f / 512.f) - mean * mean;
  const float rstd = rsqrtf(var + 1e-3f);
  float4 g1 = *(const float4*)&g[lane * 8];
  float4 g2 = *(const float4*)&g[lane * 8 + 4];
  float4 b1 = *(const float4*)&bb[lane * 8];
  float4 b2 = *(const float4*)&bb[lane * 8 + 4];
  float gg[8] = {g1.x, g1.y, g1.z, g1.w, g2.x, g2.y, g2.z, g2.w};
  float bbv[8] = {b1.x, b1.y, b1.z, b1.w, b2.x, b2.y, b2.z, b2.w};
#pragma unroll
  for (int j = 0; j < 8; ++j)
    vv[j] = (vv[j] - mean) * rstd * gg[j] + bbv[j];
  for (int aa = 0; aa < 18; ++aa) {
    float4 w1v = *(const float4*)&whT[aa * 512 + lane * 8];
    float4 w2v = *(const float4*)&whT[aa * 512 + lane * 8 + 4];
    float ww[8] = {w1v.x, w1v.y, w1v.z, w1v.w, w2v.x, w2v.y, w2v.z, w2v.w};
    float d = 0.f;
#pragma unroll
    for (int j = 0; j < 8; ++j) d += vv[j] * ww[j];
    for (int o = 32; o; o >>= 1) d += __shfl_xor(d, o);
    if (lane == 0) out[m * 18 + aa] = d;
  }
}

// ---------------- host ----------------
extern "C" void kernel_launch(void* const* d_in, const int* in_sizes, int n_in,
                              void* d_out, int out_size, void* d_ws, size_t ws_size,
                              hipStream_t stream) {
  const float* rtgs = (const float*)d_in[0];
  const float* states = (const float*)d_in[1];
  const int* actions = (const int*)d_in[2];
  const int* timesteps = (const int*)d_in[3];
  const float* W_rtg = (const float*)d_in[4];
  const float* b_rtg = (const float*)d_in[5];
  const float* conv1_w = (const float*)d_in[6];
  const float* conv1_b = (const float*)d_in[7];
  const float* conv2_w = (const float*)d_in[8];
  const float* conv2_b = (const float*)d_in[9];
  const float* conv3_w = (const float*)d_in[10];
  const float* conv3_b = (const float*)d_in[11];
  const float* dense_s_w = (const float*)d_in[12];
  const float* dense_s_b = (const float*)d_in[13];
  const float* emb_a = (const float*)d_in[14];
  const float* abs_pos = (const float*)d_in[15];
  const float* rel_pos = (const float*)d_in[16];
  const float* ln1_g = (const float*)d_in[17];
  const float* ln1_b = (const float*)d_in[18];
  const float* Wk = (const float*)d_in[19];
  const float* bk = (const float*)d_in[20];
  const float* Wq = (const float*)d_in[21];
  const float* bq = (const float*)d_in[22];
  const float* Wv = (const float*)d_in[23];
  const float* bv = (const float*)d_in[24];
  const float* ln2_g = (const float*)d_in[25];
  const float* ln2_b = (const float*)d_in[26];
  const float* W1 = (const float*)d_in[27];
  const float* b1 = (const float*)d_in[28];
  const float* W2 = (const float*)d_in[29];
  const float* b2 = (const float*)d_in[30];
  const float* lnf_g = (const float*)d_in[31];
  const float* lnf_b = (const float*)d_in[32];
  const float* W_head = (const float*)d_in[33];
  float* out = (float*)d_out;

  // workspace layout (bytes); transient region aliases dead buffers
  char* W = (char*)d_ws;
  float* x = (float*)(W + 0);                   // 5760*512 f32      11,796,480
  __bf16* h = (__bf16*)(W + 11796480);          // 5760*512 bf16      5,898,240
  __bf16* qkvT = (__bf16*)(W + 17694720);       // 6*1536*512 bf16    9,437,184
  __bf16* w1T = (__bf16*)(W + 27131904);        // 6*2048*512 bf16   12,582,912
  __bf16* w2T = (__bf16*)(W + 39714816);        // 6*512*2048 bf16   12,582,912
  __bf16* dswT = (__bf16*)(W + 52297728);       // 512*3136 bf16      3,211,264
  __bf16* c1wT = (__bf16*)(W + 55508992);       // 128*256 bf16          65,536
  __bf16* c2wT = (__bf16*)(W + 55574528);       // 128*512 bf16         131,072
  __bf16* c3wT = (__bf16*)(W + 55705600);       // 128*576 bf16         147,456
  float* whT = (float*)(W + 55853056);          // 18*512 f32            36,864
  float* bqkv = (float*)(W + 55889920);         // 6*1536 f32            36,864
  // transient region base = 55,926,784
  __bf16* c1out = (__bf16*)(W + 55926784);      // 768000*32 bf16    49,152,000
  __bf16* c2out = (__bf16*)(W + 105078784);     // 155520*64 bf16    19,906,560
  __bf16* c3out = (__bf16*)(W + 55926784);      // 94080*64 bf16     (aliases dead c1out)
  float* ste = (float*)(W + 67969024);          // 1920*512 f32      (after c3out)
  __bf16* qkvb = (__bf16*)(W + 55926784);       // 5760*1536 bf16    (aliases dead conv bufs)
  __bf16* mlph = (__bf16*)(W + 73621504);       // 5760*2048 bf16
  // end = 124,985,344 bytes

  const dim3 tb(32, 8);
  // weight transposes (BT layout) f32 -> bf16; conv1 weights absorb the /255
  transpose_pad<__bf16><<<dim3(8, 4, 1), tb, 0, stream>>>(conv1_w, c1wT, 256, 32, 128, 0, 0, 1.f / 255.f);
  transpose_pad<__bf16><<<dim3(16, 4, 1), tb, 0, stream>>>(conv2_w, c2wT, 512, 64, 128, 0, 0, 1.f);
  transpose_pad<__bf16><<<dim3(18, 4, 1), tb, 0, stream>>>(conv3_w, c3wT, 576, 64, 128, 0, 0, 1.f);
  transpose_pad<__bf16><<<dim3(98, 16, 1), tb, 0, stream>>>(dense_s_w, dswT, 3136, 512, 512, 0, 0, 1.f);
  transpose_qkv<<<dim3(16, 16, 18), tb, 0, stream>>>(Wk, Wq, Wv, qkvT);
  transpose_pad<__bf16><<<dim3(16, 64, 6), tb, 0, stream>>>(W1, w1T, 512, 2048, 2048, 512 * 2048, 2048 * 512, 1.f);
  transpose_pad<__bf16><<<dim3(64, 16, 6), tb, 0, stream>>>(W2, w2T, 2048, 512, 512, 2048 * 512, 512 * 2048, 1.f);
  transpose_pad<float><<<dim3(16, 1, 1), tb, 0, stream>>>(W_head, whT, 512, 18, 18, 0, 0, 1.f);
  biascat_k<<<6, 256, 0, stream>>>(bk, bq, bv, bqkv);

  // conv stem as implicit GEMM + dense embedding (conv GEMMs XCD-swizzled for window-overlap L2 reuse)
  conv1_k<<<6000, 256, 0, stream>>>(states, c1wT, conv1_b, c1out);
  gemm_k<2, 128, 64, 2, 2, 512, ACT_RELU, OUT_BF16, 64, 1><<<dim3(1215, 1), 256, 0, stream>>>(c1out, c2wT, conv2_b, c2out);
  gemm_k<3, 128, 64, 2, 2, 576, ACT_RELU, OUT_BF16, 64, 1><<<dim3(735, 1), 256, 0, stream>>>(c2out, c3wT, conv3_b, c3out);
  gemm_k<0, 64, 64, 2, 2, 3136, ACT_TANH, OUT_F32, 512, 0><<<dim3(30, 8), 256, 0, stream>>>(c3out, dswT, dense_s_b, (void*)ste);

  embed_k<<<11520, 256, 0, stream>>>(rtgs, actions, timesteps, W_rtg, b_rtg, emb_a, abs_pos, rel_pos, ste, x);

  for (int i = 0; i < 6; ++i) {
    ln_k<<<1440, 256, 0, stream>>>(x, ln1_g + i * 512, ln1_b + i * 512, h);
    gemm_k<0, 128, 128, 2, 2, 512, ACT_NONE, OUT_BF16, 1536, 0><<<dim3(45, 12), 256, 0, stream>>>(
        h, qkvT + (size_t)i * 1536 * 512, bqkv + i * 1536, qkvb);
    attn_k<<<512, 256, 0, stream>>>(qkvb, x);
    ln_k<<<1440, 256, 0, stream>>>(x, ln2_g + i * 512, ln2_b + i * 512, h);
    gemm_k<0, 128, 128, 2, 2, 512, ACT_GELU, OUT_BF16, 2048, 0><<<dim3(45, 16), 256, 0, stream>>>(
        h, w1T + (size_t)i * 2048 * 512, b1 + i * 2048, mlph);
    gemm_k<0, 64, 64, 2, 2, 2048, ACT_NONE, OUT_ADD, 512, 0><<<dim3(90, 8), 256, 0, stream>>>(
        mlph, w2T + (size_t)i * 2048 * 512, b2 + i * 512, x);
  }

  head_k<<<1920, 64, 0, stream>>>(x, lnf_g, lnf_b, whT, out);
}

// Round 3
// 1304.661 us; speedup vs baseline: 1.0833x; 1.0833x over previous
//
#include <hip/hip_runtime.h>
#include <hip/hip_bf16.h>

typedef __attribute__((ext_vector_type(8))) __bf16 bf16x8;
typedef __attribute__((ext_vector_type(4))) float f32x4;

#define ACT_NONE 0
#define ACT_RELU 1
#define ACT_GELU 2
#define ACT_TANH 3
#define OUT_F32 0
#define OUT_BF16 1
#define OUT_ADD 2

// ---------------- async global->LDS, 16B per lane (lane writes lds_base + lane*16) ----------------
__device__ __forceinline__ void gll16(const void* g, void* l) {
  __builtin_amdgcn_global_load_lds(
      reinterpret_cast<const __attribute__((address_space(1))) unsigned int*>(
          reinterpret_cast<unsigned long long>(g)),
      reinterpret_cast<__attribute__((address_space(3))) unsigned int*>(
          reinterpret_cast<unsigned long long>(l)),
      16, 0, 0);
}

// ---------------- bijective XCD-chunked swizzle (m204): keep adjacent blocks on one XCD L2 ----------
__device__ __forceinline__ int xcd_swz(int bid, int n) {
  const int q = n >> 3, r = n & 7, x = bid & 7, o = bid >> 3;
  return (x < r ? x * (q + 1) : r * (q + 1) + (x - r) * q) + o;
}

// ---------------- implicit-GEMM A addressing ----------------
// MODE 0: plain row-major A[M][K]
// MODE 1: conv1 im2col: input (1920,84,84,4) f32, 8x8 s4 -> k=ky*32+(kx*4+ci)
// MODE 2: conv2 im2col: input (1920,20,20,32), 4x4 s2 -> k=(ky*4+kx)*32+ci
// MODE 3: conv3 im2col: input (1920,9,9,64),  3x3 s1 -> k=(ky*3+kx)*64+ci
template<int MODE, int K>
__device__ __forceinline__ size_t a_rowbase(int m) {
  if constexpr (MODE == 0) {
    return (size_t)m * K;
  } else if constexpr (MODE == 1) {
    int img = m / 400; int p = m - img * 400; int oy = p / 20; int ox = p - oy * 20;
    return (size_t)img * 28224 + oy * 1344 + ox * 16;
  } else if constexpr (MODE == 2) {
    int img = m / 81; int p = m - img * 81; int oy = p / 9; int ox = p - oy * 9;
    return (size_t)img * 12800 + oy * 1280 + ox * 64;
  } else {
    int img = m / 49; int p = m - img * 49; int oy = p / 7; int ox = p - oy * 7;
    return (size_t)img * 5184 + oy * 576 + ox * 64;
  }
}
// wave-uniform part of im2col k-offset (lane adds lkc*8 < 32; kb is a multiple of 32,
// and 32 divides every block stride, so the division never splits a 32-chunk)
template<int MODE>
__device__ __forceinline__ int f_koff(int kb) {
  if constexpr (MODE == 0) return kb;
  else if constexpr (MODE == 2) return (kb >> 7) * 640 + ((kb >> 5) & 3) * 32;
  else return kb + (kb / 192) * 384;  // MODE 3: ky*576 + (kb - ky*192)
}

__device__ __forceinline__ bf16x8 ld8f(const float* f) {
  float4 a = *(const float4*)f;
  float4 b = *(const float4*)(f + 4);
  bf16x8 r;
  r[0] = (__bf16)a.x; r[1] = (__bf16)a.y; r[2] = (__bf16)a.z; r[3] = (__bf16)a.w;
  r[4] = (__bf16)b.x; r[5] = (__bf16)b.y; r[6] = (__bf16)b.z; r[7] = (__bf16)b.w;
  return r;
}

__device__ __forceinline__ float act_apply(float v, int ACT) {
  if (ACT == ACT_RELU) return fmaxf(v, 0.f);
  if (ACT == ACT_GELU) return 0.5f * v * (1.f + erff(v * 0.70710678118f));
  if (ACT == ACT_TANH) return tanhf(v);
  return v;
}

// ---------------- generic MFMA GEMM:  C[M][N] = act(A * BT^T + bias) ----------------
// A bf16 addressed per MODE; BT bf16 [N][K] row-major. Tile TM x TN, BK=32,
// 4 waves arranged WM x WN. global_load_lds (16B) staging, unpadded LDS rows (m97-style).
// Grid is FLAT 1-D, n-fastest: bid -> (bm = bid/NBLK, bn = bid%NBLK), optionally
// XCD-chunk-swizzled so one XCD's chunk iterates n fast / m slow -> A-panel reused NBLK x
// back-to-back in that XCD's L2, and the whole B matrix (<= 3.2 MB here) stays L2-resident.
// Requires: TM%64==0, TN%64==0, (TM/16)%4==0, (TN/16)%4==0, K%32==0, all dims exact.
template<int MODE, int TM, int TN, int WM, int WN, int K, int ACT, int OUTM, int LDC, int NBLK, int SWZ>
__global__ __launch_bounds__(256) void gemm_k(const __bf16* __restrict__ A,
                                              const __bf16* __restrict__ BT,
                                              const float* __restrict__ bias,
                                              void* __restrict__ C) {
  constexpr int SM = TM / WM, SN = TN / WN;
  constexpr int AM = SM / 16, AN = SN / 16;
  constexpr int TA = TM / 64, TB = TN / 64;  // wave-insts per wave for A / B staging
  __shared__ __align__(16) __bf16 As[TM * 32];
  __shared__ __align__(16) __bf16 Bs[TN * 32];
  const int tid = threadIdx.x;
  const int wave = tid >> 6, lane = tid & 63;
  const int quad = lane >> 4, l16 = lane & 15;
  const int wr = wave % WM, wc = wave / WM;
  const int bid = SWZ ? xcd_swz(blockIdx.x, gridDim.x) : blockIdx.x;
  const int bn = bid % NBLK, bm = bid / NBLK;
  const int m0 = bm * TM, n0 = bn * TN;
  const int lrow = lane >> 2, lkc = lane & 3;  // staging: lane -> (row, 8-elem chunk)

  const __bf16* ga[TA];
  const __bf16* gb[TB];
#pragma unroll
  for (int t = 0; t < TA; ++t)
    ga[t] = A + a_rowbase<MODE, K>(m0 + (wave + 4 * t) * 16 + lrow) + lkc * 8;
#pragma unroll
  for (int t = 0; t < TB; ++t)
    gb[t] = BT + (size_t)(n0 + (wave + 4 * t) * 16 + lrow) * K + lkc * 8;

  f32x4 acc[AM][AN] = {};
  for (int kt = 0; kt < K / 32; ++kt) {
    const int kb = kt * 32;
    const int fa = f_koff<MODE>(kb);
    __syncthreads();
#pragma unroll
    for (int t = 0; t < TA; ++t)
      gll16(ga[t] + fa, &As[(wave + 4 * t) * 16 * 32]);
#pragma unroll
    for (int t = 0; t < TB; ++t)
      gll16(gb[t] + kb, &Bs[(wave + 4 * t) * 16 * 32]);
    __syncthreads();
    bf16x8 af[AM], bf[AN];
#pragma unroll
    for (int mt = 0; mt < AM; ++mt)
      af[mt] = *(const bf16x8*)&As[(wr * SM + mt * 16 + l16) * 32 + quad * 8];
#pragma unroll
    for (int nt = 0; nt < AN; ++nt)
      bf[nt] = *(const bf16x8*)&Bs[(wc * SN + nt * 16 + l16) * 32 + quad * 8];
#pragma unroll
    for (int mt = 0; mt < AM; ++mt)
#pragma unroll
      for (int nt = 0; nt < AN; ++nt)
        acc[mt][nt] = __builtin_amdgcn_mfma_f32_16x16x32_bf16(af[mt], bf[nt], acc[mt][nt], 0, 0, 0);
  }

  // epilogue: C/D layout col=lane&15, row=quad*4+reg
#pragma unroll
  for (int nt = 0; nt < AN; ++nt) {
    const int col = n0 + wc * SN + nt * 16 + l16;
    const float bvl = bias[col];
#pragma unroll
    for (int mt = 0; mt < AM; ++mt) {
#pragma unroll
      for (int r = 0; r < 4; ++r) {
        const int row = m0 + wr * SM + mt * 16 + quad * 4 + r;
        float v = act_apply(acc[mt][nt][r] + bvl, ACT);
        const size_t off = (size_t)row * LDC + col;
        if constexpr (OUTM == OUT_F32) ((float*)C)[off] = v;
        else if constexpr (OUTM == OUT_BF16) ((__bf16*)C)[off] = (__bf16)v;
        else ((float*)C)[off] += v;
      }
    }
  }
}

// ---------------- conv1: f32 A (im2col MODE 1), 128x32 tile, K=256 ----------------
__global__ __launch_bounds__(256) void conv1_k(const float* __restrict__ A,
                                               const __bf16* __restrict__ BT,
                                               const float* __restrict__ bias,
                                               __bf16* __restrict__ C) {
  __shared__ __align__(16) __bf16 As[128 * 32];
  __shared__ __align__(16) __bf16 Bs[32 * 32];
  const int tid = threadIdx.x;
  const int wave = tid >> 6, lane = tid & 63;
  const int quad = lane >> 4, l16 = lane & 15;
  const int m0 = xcd_swz(blockIdx.x, gridDim.x) * 128;  // XCD-chunked: window overlap stays in L2
  const int lrow = lane >> 2, lkc = lane & 3;
  const int r0 = tid >> 2, k0o = (tid & 3) * 8;  // A staging: rows r0, r0+64
  const int r1 = r0 + 64;
  const size_t ar0 = a_rowbase<1, 256>(m0 + r0);
  const size_t ar1 = a_rowbase<1, 256>(m0 + r1);
  const __bf16* gB = BT + (size_t)(wave * 16 + lrow) * 256 + lkc * 8;  // used by waves 0,1

  f32x4 acc[2][2] = {};
  bf16x8 a0 = ld8f(A + ar0 + k0o);
  bf16x8 a1 = ld8f(A + ar1 + k0o);
  for (int kt = 0; kt < 8; ++kt) {
    const int kb = kt * 32;
    __syncthreads();
    if (wave < 2) gll16(gB + kb, &Bs[wave * 16 * 32]);
    *(bf16x8*)&As[r0 * 32 + k0o] = a0;
    *(bf16x8*)&As[r1 * 32 + k0o] = a1;
    __syncthreads();
    if (kt < 7) {
      const int fa = (kt + 1) * 336;  // f32 offset for k-block kt+1 (ky stride 336 floats)
      a0 = ld8f(A + ar0 + fa + k0o);
      a1 = ld8f(A + ar1 + fa + k0o);
    }
    bf16x8 af[2], bf[2];
#pragma unroll
    for (int mt = 0; mt < 2; ++mt)
      af[mt] = *(const bf16x8*)&As[(wave * 32 + mt * 16 + l16) * 32 + quad * 8];
#pragma unroll
    for (int nt = 0; nt < 2; ++nt)
      bf[nt] = *(const bf16x8*)&Bs[(nt * 16 + l16) * 32 + quad * 8];
#pragma unroll
    for (int mt = 0; mt < 2; ++mt)
#pragma unroll
      for (int nt = 0; nt < 2; ++nt)
        acc[mt][nt] = __builtin_amdgcn_mfma_f32_16x16x32_bf16(af[mt], bf[nt], acc[mt][nt], 0, 0, 0);
  }
#pragma unroll
  for (int nt = 0; nt < 2; ++nt) {
    const int col = nt * 16 + l16;
    const float bvl = bias[col];
#pragma unroll
    for (int mt = 0; mt < 2; ++mt) {
#pragma unroll
      for (int r = 0; r < 4; ++r) {
        const int row = m0 + wave * 32 + mt * 16 + quad * 4 + r;
        C[(size_t)row * 32 + col] = (__bf16)fmaxf(acc[mt][nt][r] + bvl, 0.f);
      }
    }
  }
}

// ---------------- transpose + pad (+scale): dst[Cpad][R] = src[R][C]^T, f32 src ----------------
template<typename TO>
__global__ void transpose_pad(const float* __restrict__ src, TO* __restrict__ dst,
                              int R, int C, int Cpad, long long sz, long long dz, float scale) {
  src += blockIdx.z * sz; dst += blockIdx.z * dz;
  __shared__ float t[32][33];
  const int tx = threadIdx.x, ty = threadIdx.y;
  const int r0 = blockIdx.x * 32, c0 = blockIdx.y * 32;
  for (int i = ty; i < 32; i += 8) {
    int r = r0 + i, c = c0 + tx;
    t[i][tx] = (r < R && c < C) ? src[(size_t)r * C + c] : 0.f;
  }
  __syncthreads();
  for (int i = ty; i < 32; i += 8) {
    int c = c0 + i, r = r0 + tx;
    if (c < Cpad && r < R)
      dst[(size_t)c * R + r] = (c < C) ? (TO)(t[tx][i] * scale) : (TO)0.f;
  }
}

// ---------------- merged K/Q/V weight transpose: 3 launches -> 1; all 512x512, no padding ------
__global__ void transpose_qkv(const float* __restrict__ Wk_, const float* __restrict__ Wq_,
                              const float* __restrict__ Wv_, __bf16* __restrict__ dst) {
  const int z = blockIdx.z, which = z / 6, i = z - which * 6;  // grid z = 18
  const float* src = (which == 0 ? Wk_ : which == 1 ? Wq_ : Wv_) + (size_t)i * 512 * 512;
  __bf16* d = dst + (size_t)i * 1536 * 512 + (size_t)which * 512 * 512;
  __shared__ float t[32][33];
  const int tx = threadIdx.x, ty = threadIdx.y;
  const int r0 = blockIdx.x * 32, c0 = blockIdx.y * 32;
  for (int j = ty; j < 32; j += 8)
    t[j][tx] = src[(size_t)(r0 + j) * 512 + c0 + tx];
  __syncthreads();
  for (int j = ty; j < 32; j += 8)
    d[(size_t)(c0 + j) * 512 + r0 + tx] = (__bf16)t[tx][j];
}

__global__ void biascat_k(const float* bk, const float* bq, const float* bv, float* dst) {
  const int i = blockIdx.x;
  for (int d = threadIdx.x; d < 512; d += 256) {
    dst[i * 1536 + d] = bk[i * 512 + d];
    dst[i * 1536 + 512 + d] = bq[i * 512 + d];
    dst[i * 1536 + 1024 + d] = bv[i * 512 + d];
  }
}

// ---------------- token embedding: x = interleave(rtg_e, st_e, a_e) + pos ----------------
__global__ void embed_k(const float* __restrict__ rtgs, const int* __restrict__ actions,
                        const int* __restrict__ timesteps, const float* __restrict__ W_rtg,
                        const float* __restrict__ b_rtg, const float* __restrict__ emb_a,
                        const float* __restrict__ abs_pos, const float* __restrict__ rel_pos,
                        const float* __restrict__ ste, float* __restrict__ x) {
  const int idx = blockIdx.x * 256 + threadIdx.x;  // 64*90*512 total
  const int d = idx & 511; const int rb = idx >> 9;
  const int b = rb / 90, t = rb - b * 90;
  const int l = t / 3, r = t - l * 3;
  const float pos = rel_pos[t * 512 + d] + abs_pos[(size_t)timesteps[b] * 512 + d];
  float tok;
  if (r == 0) tok = tanhf(rtgs[b * 30 + l] * W_rtg[d] + b_rtg[d]);
  else if (r == 1) tok = ste[(size_t)(b * 30 + l) * 512 + d];
  else tok = tanhf(emb_a[actions[b * 30 + l] * 512 + d]);
  x[idx] = tok + pos;
}

// ---------------- layernorm: h_bf16 = LN(x_f32) * g + b, one wave per row ----------------
__global__ __launch_bounds__(256) void ln_k(const float* __restrict__ x, const float* __restrict__ g,
                                            const float* __restrict__ bb, __bf16* __restrict__ h) {
  const int row = blockIdx.x * 4 + (threadIdx.x >> 6);
  const int lane = threadIdx.x & 63;
  const float* xr = x + (size_t)row * 512;
  float4 a = *(const float4*)&xr[lane * 8];
  float4 c = *(const float4*)&xr[lane * 8 + 4];
  float vv[8] = {a.x, a.y, a.z, a.w, c.x, c.y, c.z, c.w};
  float s = 0.f, q = 0.f;
#pragma unroll
  for (int j = 0; j < 8; ++j) { s += vv[j]; q += vv[j] * vv[j]; }
  for (int o = 32; o; o >>= 1) { s += __shfl_xor(s, o); q += __shfl_xor(q, o); }
  const float mean = s * (1.f / 512.f);
  const float var = q * (1.f / 512.f) - mean * mean;
  const float rstd = rsqrtf(var + 1e-3f);
  float4 g1 = *(const float4*)&g[lane * 8];
  float4 g2 = *(const float4*)&g[lane * 8 + 4];
  float4 b1 = *(const float4*)&bb[lane * 8];
  float4 b2 = *(const float4*)&bb[lane * 8 + 4];
  float gg[8] = {g1.x, g1.y, g1.z, g1.w, g2.x, g2.y, g2.z, g2.w};
  float bbv[8] = {b1.x, b1.y, b1.z, b1.w, b2.x, b2.y, b2.z, b2.w};
  bf16x8 ov;
#pragma unroll
  for (int j = 0; j < 8; ++j)
    ov[j] = (__bf16)((vv[j] - mean) * rstd * gg[j] + bbv[j]);
  *(bf16x8*)&h[(size_t)row * 512 + lane * 8] = ov;
}

// ---------------- fused attention per (b,h): s=K@Q^T/8 masked, softmax, o=W@V, x += o ----------
// V global loads issued at kernel entry (registers), LDS-written only at the barrier before PV:
// hides the V HBM latency under scores+softmax instead of serializing it after softmax.
__global__ __launch_bounds__(256) void attn_k(const __bf16* __restrict__ qkv, float* __restrict__ x) {
  __shared__ __align__(16) char smem[64512];
  __bf16* kS = (__bf16*)smem;              // [96][72]  13824B
  __bf16* qS = (__bf16*)(smem + 13824);    // [96][72]  13824B
  __bf16* wS = (__bf16*)smem;              // [96][104] 19968B (reuses k/q after scores)
  float* sS = (float*)(smem + 27648);      // [96][96]  36864B
  __bf16* vT = (__bf16*)(smem + 27648);    // [64][104] 13312B (reuses sS after softmax)

  const int tid = threadIdx.x;
  const int b = blockIdx.x >> 3, h = blockIdx.x & 7;
  const int wave = tid >> 6, lane = tid & 63, quad = lane >> 4, l16 = lane & 15;
  const size_t rowbase = (size_t)b * 90 * 1536 + h * 64;

  // phase 0: issue V loads into registers (consumed in phase 4; latency hidden under phases 1-3)
  bf16x8 vreg[3];
#pragma unroll
  for (int it = 0; it < 3; ++it) {
    const int c = tid + it * 256, t = c >> 3, d8 = (c & 7) * 8;
#pragma unroll
    for (int j = 0; j < 8; ++j) vreg[it][j] = (__bf16)0.f;
    if (t < 90) vreg[it] = *(const bf16x8*)(qkv + rowbase + (size_t)t * 1536 + 1024 + d8);
  }

  // phase 1: load K, Q tiles (zero-pad rows 90..95)
  for (int c = tid; c < 768; c += 256) {
    const int t = c >> 3, d8 = (c & 7) * 8;
    bf16x8 kv, qv;
#pragma unroll
    for (int j = 0; j < 8; ++j) { kv[j] = (__bf16)0.f; qv[j] = (__bf16)0.f; }
    if (t < 90) {
      const __bf16* src = qkv + rowbase + (size_t)t * 1536 + d8;
      kv = *(const bf16x8*)src;
      qv = *(const bf16x8*)(src + 512);
    }
    *(bf16x8*)&kS[t * 72 + d8] = kv;
    *(bf16x8*)&qS[t * 72 + d8] = qv;
  }
  __syncthreads();

  // phase 2: s[i][j] = sum_d k[i,d] q[j,d] / 8, causal mask j<=i
  for (int tt = wave; tt < 36; tt += 4) {
    const int it = tt / 6, jt = tt - it * 6;
    f32x4 acc = {0.f, 0.f, 0.f, 0.f};
#pragma unroll
    for (int ks = 0; ks < 2; ++ks) {
      bf16x8 af = *(const bf16x8*)&kS[(it * 16 + l16) * 72 + ks * 32 + quad * 8];
      bf16x8 bq = *(const bf16x8*)&qS[(jt * 16 + l16) * 72 + ks * 32 + quad * 8];
      acc = __builtin_amdgcn_mfma_f32_16x16x32_bf16(af, bq, acc, 0, 0, 0);
    }
    const int col = jt * 16 + l16;
#pragma unroll
    for (int r = 0; r < 4; ++r) {
      const int row = it * 16 + quad * 4 + r;
      sS[row * 96 + col] = (col <= row && col < 90) ? acc[r] * 0.125f : -1e30f;
    }
  }
  __syncthreads();

  // phase 3: row softmax -> wS (bf16)
  for (int row = wave; row < 96; row += 4) {
    const float e0 = sS[row * 96 + lane];
    const float e1 = (lane < 32) ? sS[row * 96 + 64 + lane] : -1e30f;
    float m = fmaxf(e0, e1);
    for (int o = 32; o; o >>= 1) m = fmaxf(m, __shfl_xor(m, o));
    const float p0 = __expf(e0 - m);
    const float p1 = (lane < 32) ? __expf(e1 - m) : 0.f;
    float s = p0 + p1;
    for (int o = 32; o; o >>= 1) s += __shfl_xor(s, o);
    const float inv = 1.f / s;
    wS[row * 104 + lane] = (__bf16)(p0 * inv);
    if (lane < 32) wS[row * 104 + 64 + lane] = (__bf16)(p1 * inv);
  }
  __syncthreads();

  // phase 4: write preloaded V transposed into vT[d][j] (zero-pad cols 90..95)
#pragma unroll
  for (int it = 0; it < 3; ++it) {
    const int c = tid + it * 256, t = c >> 3, d8 = (c & 7) * 8;
#pragma unroll
    for (int j = 0; j < 8; ++j) vT[(d8 + j) * 104 + t] = vreg[it][j];
  }
  __syncthreads();

  // phase 5: o[i][d] = sum_j w[i,j] v[j,d]; x[b, i, h*64+d] += o
  for (int tt = wave; tt < 24; tt += 4) {
    const int it = tt >> 2, dt = tt & 3;
    f32x4 acc = {0.f, 0.f, 0.f, 0.f};
#pragma unroll
    for (int ks = 0; ks < 3; ++ks) {
      bf16x8 aw = *(const bf16x8*)&wS[(it * 16 + l16) * 104 + ks * 32 + quad * 8];
      bf16x8 bv = *(const bf16x8*)&vT[(dt * 16 + l16) * 104 + ks * 32 + quad * 8];
      acc = __builtin_amdgcn_mfma_f32_16x16x32_bf16(aw, bv, acc, 0, 0, 0);
    }
    const int d = dt * 16 + l16;
#pragma unroll
    for (int r = 0; r < 4; ++r) {
      const int i = it * 16 + quad * 4 + r;
      if (i < 90) {
        float* p = x + (size_t)(b * 90 + i) * 512 + h * 64 + d;
        *p += acc[r];
      }
    }
  }
}

// ---------------- fused final LN + head (state tokens only), 1 wave per output row ----------------
__global__ __launch_bounds__(64) void head_k(const float* __restrict__ x, const float* __restrict__ g,
                                             const float* __restrict__ bb, const float* __restrict__ whT,
                                             float* __restrict__ out) {
  const int m = blockIdx.x;  // 0..1919 = b*30+l
  const int b = m / 30, l = m - b * 30;
  const float* xr = x + (size_t)(b * 90 + 3 * l + 1) * 512;
  const int lane = threadIdx.x;
  float4 a = *(const float4*)&xr[lane * 8];
  float4 c = *(const float4*)&xr[lane * 8 + 4];
  float vv[8] = {a.x, a.y, a.z, a.w, c.x, c.y, c.z, c.w};
  float s = 0.f, q = 0.f;
#pragma unroll
  for (int j = 0; j < 8; ++j) { s += vv[j]; q += vv[j] * vv[j]; }
  for (int o = 32; o; o >>= 1) { s += __shfl_xor(s, o); q += __shfl_xor(q, o); }
  const float mean = s * (1.f / 512.f);
  const float var = q * (1.f / 512.f) - mean * mean;
  const float rstd = rsqrtf(var + 1e-3f);
  float4 g1 = *(const float4*)&g[lane * 8];
  float4 g2 = *(const float4*)&g[lane * 8 + 4];
  float4 b1 = *(const float4*)&bb[lane * 8];
  float4 b2 = *(const float4*)&bb[lane * 8 + 4];
  float gg[8] = {g1.x, g1.y, g1.z, g1.w, g2.x, g2.y, g2.z, g2.w};
  float bbv[8] = {b1.x, b1.y, b1.z, b1.w, b2.x, b2.y, b2.z, b2.w};
#pragma unroll
  for (int j = 0; j < 8; ++j)
    vv[j] = (vv[j] - mean) * rstd * gg[j] + bbv[j];
  for (int aa = 0; aa < 18; ++aa) {
    float4 w1v = *(const float4*)&whT[aa * 512 + lane * 8];
    float4 w2v = *(const float4*)&whT[aa * 512 + lane * 8 + 4];
    float ww[8] = {w1v.x, w1v.y, w1v.z, w1v.w, w2v.x, w2v.y, w2v.z, w2v.w};
    float d = 0.f;
#pragma unroll
    for (int j = 0; j < 8; ++j) d += vv[j] * ww[j];
    for (int o = 32; o; o >>= 1) d += __shfl_xor(d, o);
    if (lane == 0) out[m * 18 + aa] = d;
  }
}

// ---------------- host ----------------
extern "C" void kernel_launch(void* const* d_in, const int* in_sizes, int n_in,
                              void* d_out, int out_size, void* d_ws, size_t ws_size,
                              hipStream_t stream) {
  const float* rtgs = (const float*)d_in[0];
  const float* states = (const float*)d_in[1];
  const int* actions = (const int*)d_in[2];
  const int* timesteps = (const int*)d_in[3];
  const float* W_rtg = (const float*)d_in[4];
  const float* b_rtg = (const float*)d_in[5];
  const float* conv1_w = (const float*)d_in[6];
  const float* conv1_b = (const float*)d_in[7];
  const float* conv2_w = (const float*)d_in[8];
  const float* conv2_b = (const float*)d_in[9];
  const float* conv3_w = (const float*)d_in[10];
  const float* conv3_b = (const float*)d_in[11];
  const float* dense_s_w = (const float*)d_in[12];
  const float* dense_s_b = (const float*)d_in[13];
  const float* emb_a = (const float*)d_in[14];
  const float* abs_pos = (const float*)d_in[15];
  const float* rel_pos = (const float*)d_in[16];
  const float* ln1_g = (const float*)d_in[17];
  const float* ln1_b = (const float*)d_in[18];
  const float* Wk = (const float*)d_in[19];
  const float* bk = (const float*)d_in[20];
  const float* Wq = (const float*)d_in[21];
  const float* bq = (const float*)d_in[22];
  const float* Wv = (const float*)d_in[23];
  const float* bv = (const float*)d_in[24];
  const float* ln2_g = (const float*)d_in[25];
  const float* ln2_b = (const float*)d_in[26];
  const float* W1 = (const float*)d_in[27];
  const float* b1 = (const float*)d_in[28];
  const float* W2 = (const float*)d_in[29];
  const float* b2 = (const float*)d_in[30];
  const float* lnf_g = (const float*)d_in[31];
  const float* lnf_b = (const float*)d_in[32];
  const float* W_head = (const float*)d_in[33];
  float* out = (float*)d_out;

  // workspace layout (bytes); transient region aliases dead buffers
  char* W = (char*)d_ws;
  float* x = (float*)(W + 0);                   // 5760*512 f32      11,796,480
  __bf16* h = (__bf16*)(W + 11796480);          // 5760*512 bf16      5,898,240
  __bf16* qkvT = (__bf16*)(W + 17694720);       // 6*1536*512 bf16    9,437,184
  __bf16* w1T = (__bf16*)(W + 27131904);        // 6*2048*512 bf16   12,582,912
  __bf16* w2T = (__bf16*)(W + 39714816);        // 6*512*2048 bf16   12,582,912
  __bf16* dswT = (__bf16*)(W + 52297728);       // 512*3136 bf16      3,211,264
  __bf16* c1wT = (__bf16*)(W + 55508992);       // 128*256 bf16          65,536
  __bf16* c2wT = (__bf16*)(W + 55574528);       // 128*512 bf16         131,072
  __bf16* c3wT = (__bf16*)(W + 55705600);       // 128*576 bf16         147,456
  float* whT = (float*)(W + 55853056);          // 18*512 f32            36,864
  float* bqkv = (float*)(W + 55889920);         // 6*1536 f32            36,864
  // transient region base = 55,926,784
  __bf16* c1out = (__bf16*)(W + 55926784);      // 768000*32 bf16    49,152,000
  __bf16* c2out = (__bf16*)(W + 105078784);     // 155520*64 bf16    19,906,560
  __bf16* c3out = (__bf16*)(W + 55926784);      // 94080*64 bf16     (aliases dead c1out)
  float* ste = (float*)(W + 67969024);          // 1920*512 f32      (after c3out)
  __bf16* qkvb = (__bf16*)(W + 55926784);       // 5760*1536 bf16    (aliases dead conv bufs)
  __bf16* mlph = (__bf16*)(W + 73621504);       // 5760*2048 bf16
  // end = 124,985,344 bytes

  const dim3 tb(32, 8);
  // weight transposes (BT layout) f32 -> bf16; conv1 weights absorb the /255
  transpose_pad<__bf16><<<dim3(8, 4, 1), tb, 0, stream>>>(conv1_w, c1wT, 256, 32, 128, 0, 0, 1.f / 255.f);
  transpose_pad<__bf16><<<dim3(16, 4, 1), tb, 0, stream>>>(conv2_w, c2wT, 512, 64, 128, 0, 0, 1.f);
  transpose_pad<__bf16><<<dim3(18, 4, 1), tb, 0, stream>>>(conv3_w, c3wT, 576, 64, 128, 0, 0, 1.f);
  transpose_pad<__bf16><<<dim3(98, 16, 1), tb, 0, stream>>>(dense_s_w, dswT, 3136, 512, 512, 0, 0, 1.f);
  transpose_qkv<<<dim3(16, 16, 18), tb, 0, stream>>>(Wk, Wq, Wv, qkvT);
  transpose_pad<__bf16><<<dim3(16, 64, 6), tb, 0, stream>>>(W1, w1T, 512, 2048, 2048, 512 * 2048, 2048 * 512, 1.f);
  transpose_pad<__bf16><<<dim3(64, 16, 6), tb, 0, stream>>>(W2, w2T, 2048, 512, 512, 2048 * 512, 512 * 2048, 1.f);
  transpose_pad<float><<<dim3(16, 1, 1), tb, 0, stream>>>(W_head, whT, 512, 18, 18, 0, 0, 1.f);
  biascat_k<<<6, 256, 0, stream>>>(bk, bq, bv, bqkv);

  // conv stem as implicit GEMM + dense embedding (all GEMMs: flat n-fastest grid, XCD-chunked)
  conv1_k<<<6000, 256, 0, stream>>>(states, c1wT, conv1_b, c1out);
  gemm_k<2, 128, 64, 2, 2, 512, ACT_RELU, OUT_BF16, 64, 1, 1><<<1215, 256, 0, stream>>>(c1out, c2wT, conv2_b, c2out);
  gemm_k<3, 128, 64, 2, 2, 576, ACT_RELU, OUT_BF16, 64, 1, 1><<<735, 256, 0, stream>>>(c2out, c3wT, conv3_b, c3out);
  gemm_k<0, 64, 64, 2, 2, 3136, ACT_TANH, OUT_F32, 512, 8, 1><<<240, 256, 0, stream>>>(c3out, dswT, dense_s_b, (void*)ste);

  embed_k<<<11520, 256, 0, stream>>>(rtgs, actions, timesteps, W_rtg, b_rtg, emb_a, abs_pos, rel_pos, ste, x);

  for (int i = 0; i < 6; ++i) {
    ln_k<<<1440, 256, 0, stream>>>(x, ln1_g + i * 512, ln1_b + i * 512, h);
    gemm_k<0, 128, 128, 2, 2, 512, ACT_NONE, OUT_BF16, 1536, 12, 1><<<540, 256, 0, stream>>>(
        h, qkvT + (size_t)i * 1536 * 512, bqkv + i * 1536, qkvb);
    attn_k<<<512, 256, 0, stream>>>(qkvb, x);
    ln_k<<<1440, 256, 0, stream>>>(x, ln2_g + i * 512, ln2_b + i * 512, h);
    gemm_k<0, 128, 128, 2, 2, 512, ACT_GELU, OUT_BF16, 2048, 16, 1><<<720, 256, 0, stream>>>(
        h, w1T + (size_t)i * 2048 * 512, b1 + i * 2048, mlph);
    gemm_k<0, 64, 64, 2, 2, 2048, ACT_NONE, OUT_ADD, 512, 8, 1><<<720, 256, 0, stream>>>(
        mlph, w2T + (size_t)i * 2048 * 512, b2 + i * 512, x);
  }

  head_k<<<1920, 64, 0, stream>>>(x, lnf_g, lnf_b, whT, out);
}

// Round 4
// 1294.045 us; speedup vs baseline: 1.0921x; 1.0082x over previous
//
#include <hip/hip_runtime.h>
#include <hip/hip_bf16.h>

typedef __attribute__((ext_vector_type(8))) __bf16 bf16x8;
typedef __attribute__((ext_vector_type(4))) float f32x4;

#define ACT_NONE 0
#define ACT_RELU 1
#define ACT_GELU 2
#define ACT_TANH 3
#define OUT_F32 0
#define OUT_BF16 1
#define OUT_ADD 2

// ---------------- async global->LDS, 16B per lane (lane writes lds_base + lane*16) ----------------
__device__ __forceinline__ void gll16(const void* g, void* l) {
  __builtin_amdgcn_global_load_lds(
      reinterpret_cast<const __attribute__((address_space(1))) unsigned int*>(
          reinterpret_cast<unsigned long long>(g)),
      reinterpret_cast<__attribute__((address_space(3))) unsigned int*>(
          reinterpret_cast<unsigned long long>(l)),
      16, 0, 0);
}

// ---------------- bijective XCD-chunked swizzle (m204): keep adjacent blocks on one XCD L2 ----------
__device__ __forceinline__ int xcd_swz(int bid, int n) {
  const int q = n >> 3, r = n & 7, x = bid & 7, o = bid >> 3;
  return (x < r ? x * (q + 1) : r * (q + 1) + (x - r) * q) + o;
}

// ---------------- implicit-GEMM A addressing ----------------
// MODE 0: plain row-major A[M][K]
// MODE 1: conv1 im2col: input (1920,84,84,4) f32, 8x8 s4 -> k=ky*32+(kx*4+ci)
// MODE 2: conv2 im2col: input (1920,20,20,32), 4x4 s2 -> k=(ky*4+kx)*32+ci
// MODE 3: conv3 im2col: input (1920,9,9,64),  3x3 s1 -> k=(ky*3+kx)*64+ci
template<int MODE, int K>
__device__ __forceinline__ size_t a_rowbase(int m) {
  if constexpr (MODE == 0) {
    return (size_t)m * K;
  } else if constexpr (MODE == 1) {
    int img = m / 400; int p = m - img * 400; int oy = p / 20; int ox = p - oy * 20;
    return (size_t)img * 28224 + oy * 1344 + ox * 16;
  } else if constexpr (MODE == 2) {
    int img = m / 81; int p = m - img * 81; int oy = p / 9; int ox = p - oy * 9;
    return (size_t)img * 12800 + oy * 1280 + ox * 64;
  } else {
    int img = m / 49; int p = m - img * 49; int oy = p / 7; int ox = p - oy * 7;
    return (size_t)img * 5184 + oy * 576 + ox * 64;
  }
}
// wave-uniform part of im2col k-offset (lane adds lkc*8 < 32; kb is a multiple of 32,
// and 32 divides every block stride, so the division never splits a 32-chunk)
template<int MODE>
__device__ __forceinline__ int f_koff(int kb) {
  if constexpr (MODE == 0) return kb;
  else if constexpr (MODE == 2) return (kb >> 7) * 640 + ((kb >> 5) & 3) * 32;
  else return kb + (kb / 192) * 384;  // MODE 3: ky*576 + (kb - ky*192)
}

__device__ __forceinline__ bf16x8 ld8f(const float* f) {
  float4 a = *(const float4*)f;
  float4 b = *(const float4*)(f + 4);
  bf16x8 r;
  r[0] = (__bf16)a.x; r[1] = (__bf16)a.y; r[2] = (__bf16)a.z; r[3] = (__bf16)a.w;
  r[4] = (__bf16)b.x; r[5] = (__bf16)b.y; r[6] = (__bf16)b.z; r[7] = (__bf16)b.w;
  return r;
}

__device__ __forceinline__ float act_apply(float v, int ACT) {
  if (ACT == ACT_RELU) return fmaxf(v, 0.f);
  if (ACT == ACT_GELU) return 0.5f * v * (1.f + erff(v * 0.70710678118f));
  if (ACT == ACT_TANH) return tanhf(v);
  return v;
}

// ---------------- generic MFMA GEMM:  C[M][N] = act(A * BT^T + bias) ----------------
// A bf16 addressed per MODE; BT bf16 [N][K] row-major. Tile TM x TN, BK=32,
// 4 waves arranged WM x WN. global_load_lds (16B) staging, unpadded LDS rows (m97-style).
// Grid is FLAT 1-D, n-fastest: bid -> (bm = bid/NBLK, bn = bid%NBLK), optionally
// XCD-chunk-swizzled so one XCD's chunk iterates n fast / m slow -> A-panel reused NBLK x
// back-to-back in that XCD's L2, and the whole B matrix (<= 3.2 MB here) stays L2-resident.
// Requires: TM%64==0, TN%64==0, (TM/16)%4==0, (TN/16)%4==0, K%32==0, all dims exact.
template<int MODE, int TM, int TN, int WM, int WN, int K, int ACT, int OUTM, int LDC, int NBLK, int SWZ>
__global__ __launch_bounds__(256) void gemm_k(const __bf16* __restrict__ A,
                                              const __bf16* __restrict__ BT,
                                              const float* __restrict__ bias,
                                              void* __restrict__ C) {
  constexpr int SM = TM / WM, SN = TN / WN;
  constexpr int AM = SM / 16, AN = SN / 16;
  constexpr int TA = TM / 64, TB = TN / 64;  // wave-insts per wave for A / B staging
  __shared__ __align__(16) __bf16 As[TM * 32];
  __shared__ __align__(16) __bf16 Bs[TN * 32];
  const int tid = threadIdx.x;
  const int wave = tid >> 6, lane = tid & 63;
  const int quad = lane >> 4, l16 = lane & 15;
  const int wr = wave % WM, wc = wave / WM;
  const int bid = SWZ ? xcd_swz(blockIdx.x, gridDim.x) : blockIdx.x;
  const int bn = bid % NBLK, bm = bid / NBLK;
  const int m0 = bm * TM, n0 = bn * TN;
  const int lrow = lane >> 2, lkc = lane & 3;  // staging: lane -> (row, 8-elem chunk)

  const __bf16* ga[TA];
  const __bf16* gb[TB];
#pragma unroll
  for (int t = 0; t < TA; ++t)
    ga[t] = A + a_rowbase<MODE, K>(m0 + (wave + 4 * t) * 16 + lrow) + lkc * 8;
#pragma unroll
  for (int t = 0; t < TB; ++t)
    gb[t] = BT + (size_t)(n0 + (wave + 4 * t) * 16 + lrow) * K + lkc * 8;

  f32x4 acc[AM][AN] = {};
  for (int kt = 0; kt < K / 32; ++kt) {
    const int kb = kt * 32;
    const int fa = f_koff<MODE>(kb);
    __syncthreads();
#pragma unroll
    for (int t = 0; t < TA; ++t)
      gll16(ga[t] + fa, &As[(wave + 4 * t) * 16 * 32]);
#pragma unroll
    for (int t = 0; t < TB; ++t)
      gll16(gb[t] + kb, &Bs[(wave + 4 * t) * 16 * 32]);
    __syncthreads();
    bf16x8 af[AM], bf[AN];
#pragma unroll
    for (int mt = 0; mt < AM; ++mt)
      af[mt] = *(const bf16x8*)&As[(wr * SM + mt * 16 + l16) * 32 + quad * 8];
#pragma unroll
    for (int nt = 0; nt < AN; ++nt)
      bf[nt] = *(const bf16x8*)&Bs[(wc * SN + nt * 16 + l16) * 32 + quad * 8];
#pragma unroll
    for (int mt = 0; mt < AM; ++mt)
#pragma unroll
      for (int nt = 0; nt < AN; ++nt)
        acc[mt][nt] = __builtin_amdgcn_mfma_f32_16x16x32_bf16(af[mt], bf[nt], acc[mt][nt], 0, 0, 0);
  }

  // epilogue: C/D layout col=lane&15, row=quad*4+reg
#pragma unroll
  for (int nt = 0; nt < AN; ++nt) {
    const int col = n0 + wc * SN + nt * 16 + l16;
    const float bvl = bias[col];
#pragma unroll
    for (int mt = 0; mt < AM; ++mt) {
#pragma unroll
      for (int r = 0; r < 4; ++r) {
        const int row = m0 + wr * SM + mt * 16 + quad * 4 + r;
        float v = act_apply(acc[mt][nt][r] + bvl, ACT);
        const size_t off = (size_t)row * LDC + col;
        if constexpr (OUTM == OUT_F32) ((float*)C)[off] = v;
        else if constexpr (OUTM == OUT_BF16) ((__bf16*)C)[off] = (__bf16)v;
        else ((float*)C)[off] += v;
      }
    }
  }
}

// ---------------- conv1: f32 A (im2col MODE 1), 128x32 tile, K=256 ----------------
__global__ __launch_bounds__(256) void conv1_k(const float* __restrict__ A,
                                               const __bf16* __restrict__ BT,
                                               const float* __restrict__ bias,
                                               __bf16* __restrict__ C) {
  __shared__ __align__(16) __bf16 As[128 * 32];
  __shared__ __align__(16) __bf16 Bs[32 * 32];
  const int tid = threadIdx.x;
  const int wave = tid >> 6, lane = tid & 63;
  const int quad = lane >> 4, l16 = lane & 15;
  const int m0 = xcd_swz(blockIdx.x, gridDim.x) * 128;  // XCD-chunked: window overlap stays in L2
  const int lrow = lane >> 2, lkc = lane & 3;
  const int r0 = tid >> 2, k0o = (tid & 3) * 8;  // A staging: rows r0, r0+64
  const int r1 = r0 + 64;
  const size_t ar0 = a_rowbase<1, 256>(m0 + r0);
  const size_t ar1 = a_rowbase<1, 256>(m0 + r1);
  const __bf16* gB = BT + (size_t)(wave * 16 + lrow) * 256 + lkc * 8;  // used by waves 0,1

  f32x4 acc[2][2] = {};
  bf16x8 a0 = ld8f(A + ar0 + k0o);
  bf16x8 a1 = ld8f(A + ar1 + k0o);
  for (int kt = 0; kt < 8; ++kt) {
    const int kb = kt * 32;
    __syncthreads();
    if (wave < 2) gll16(gB + kb, &Bs[wave * 16 * 32]);
    *(bf16x8*)&As[r0 * 32 + k0o] = a0;
    *(bf16x8*)&As[r1 * 32 + k0o] = a1;
    __syncthreads();
    if (kt < 7) {
      const int fa = (kt + 1) * 336;  // f32 offset for k-block kt+1 (ky stride 336 floats)
      a0 = ld8f(A + ar0 + fa + k0o);
      a1 = ld8f(A + ar1 + fa + k0o);
    }
    bf16x8 af[2], bf[2];
#pragma unroll
    for (int mt = 0; mt < 2; ++mt)
      af[mt] = *(const bf16x8*)&As[(wave * 32 + mt * 16 + l16) * 32 + quad * 8];
#pragma unroll
    for (int nt = 0; nt < 2; ++nt)
      bf[nt] = *(const bf16x8*)&Bs[(nt * 16 + l16) * 32 + quad * 8];
#pragma unroll
    for (int mt = 0; mt < 2; ++mt)
#pragma unroll
      for (int nt = 0; nt < 2; ++nt)
        acc[mt][nt] = __builtin_amdgcn_mfma_f32_16x16x32_bf16(af[mt], bf[nt], acc[mt][nt], 0, 0, 0);
  }
#pragma unroll
  for (int nt = 0; nt < 2; ++nt) {
    const int col = nt * 16 + l16;
    const float bvl = bias[col];
#pragma unroll
    for (int mt = 0; mt < 2; ++mt) {
#pragma unroll
      for (int r = 0; r < 4; ++r) {
        const int row = m0 + wave * 32 + mt * 16 + quad * 4 + r;
        C[(size_t)row * 32 + col] = (__bf16)fmaxf(acc[mt][nt][r] + bvl, 0.f);
      }
    }
  }
}

// ---------------- transpose + pad (+scale): dst[Cpad][R] = src[R][C]^T, f32 src ----------------
template<typename TO>
__global__ void transpose_pad(const float* __restrict__ src, TO* __restrict__ dst,
                              int R, int C, int Cpad, long long sz, long long dz, float scale) {
  src += blockIdx.z * sz; dst += blockIdx.z * dz;
  __shared__ float t[32][33];
  const int tx = threadIdx.x, ty = threadIdx.y;
  const int r0 = blockIdx.x * 32, c0 = blockIdx.y * 32;
  for (int i = ty; i < 32; i += 8) {
    int r = r0 + i, c = c0 + tx;
    t[i][tx] = (r < R && c < C) ? src[(size_t)r * C + c] : 0.f;
  }
  __syncthreads();
  for (int i = ty; i < 32; i += 8) {
    int c = c0 + i, r = r0 + tx;
    if (c < Cpad && r < R)
      dst[(size_t)c * R + r] = (c < C) ? (TO)(t[tx][i] * scale) : (TO)0.f;
  }
}

// ---------------- merged K/Q/V weight transpose, HEAD-GROUPED output ----------------
// dst row for source col c of W{k,q,v}: (c>>6)*192 + which*64 + (c&63)
// -> layer layout [h][K(64)|Q(64)|V(64)][512]: one head's 192 B-rows contiguous.
__global__ void transpose_qkv(const float* __restrict__ Wk_, const float* __restrict__ Wq_,
                              const float* __restrict__ Wv_, __bf16* __restrict__ dst) {
  const int z = blockIdx.z, which = z / 6, i = z - which * 6;  // grid z = 18
  const float* src = (which == 0 ? Wk_ : which == 1 ? Wq_ : Wv_) + (size_t)i * 512 * 512;
  __bf16* d = dst + (size_t)i * 1536 * 512;
  __shared__ float t[32][33];
  const int tx = threadIdx.x, ty = threadIdx.y;
  const int r0 = blockIdx.x * 32, c0 = blockIdx.y * 32;
  for (int j = ty; j < 32; j += 8)
    t[j][tx] = src[(size_t)(r0 + j) * 512 + c0 + tx];
  __syncthreads();
  for (int j = ty; j < 32; j += 8) {
    const int c = c0 + j;
    const int row = ((c >> 6) * 192) + which * 64 + (c & 63);
    d[(size_t)row * 512 + r0 + tx] = (__bf16)t[tx][j];
  }
}

// head-grouped bias concat: dst[i][h*192 + which*64 + hd]
__global__ void biascat_k(const float* bk, const float* bq, const float* bv, float* dst) {
  const int i = blockIdx.x;
  for (int d = threadIdx.x; d < 512; d += 256) {
    const int g = (d >> 6) * 192 + (d & 63);
    dst[i * 1536 + g] = bk[i * 512 + d];
    dst[i * 1536 + g + 64] = bq[i * 512 + d];
    dst[i * 1536 + g + 128] = bv[i * 512 + d];
  }
}

// ---------------- token embedding: x = interleave(rtg_e, st_e, a_e) + pos; 96-row stride/b ------
__global__ void embed_k(const float* __restrict__ rtgs, const int* __restrict__ actions,
                        const int* __restrict__ timesteps, const float* __restrict__ W_rtg,
                        const float* __restrict__ b_rtg, const float* __restrict__ emb_a,
                        const float* __restrict__ abs_pos, const float* __restrict__ rel_pos,
                        const float* __restrict__ ste, float* __restrict__ x) {
  const int idx = blockIdx.x * 256 + threadIdx.x;  // 64*96*512 total
  const int d = idx & 511; const int rb = idx >> 9;
  const int b = rb / 96, t = rb - b * 96;
  if (t >= 90) { x[idx] = 0.f; return; }  // pad rows: finite zeros (downstream-safe)
  const int l = t / 3, r = t - l * 3;
  const float pos = rel_pos[t * 512 + d] + abs_pos[(size_t)timesteps[b] * 512 + d];
  float tok;
  if (r == 0) tok = tanhf(rtgs[b * 30 + l] * W_rtg[d] + b_rtg[d]);
  else if (r == 1) tok = ste[(size_t)(b * 30 + l) * 512 + d];
  else tok = tanhf(emb_a[actions[b * 30 + l] * 512 + d]);
  x[idx] = tok + pos;
}

// ---------------- layernorm: h_bf16 = LN(x_f32) * g + b, one wave per row ----------------
__global__ __launch_bounds__(256) void ln_k(const float* __restrict__ x, const float* __restrict__ g,
                                            const float* __restrict__ bb, __bf16* __restrict__ h) {
  const int row = blockIdx.x * 4 + (threadIdx.x >> 6);
  const int lane = threadIdx.x & 63;
  const float* xr = x + (size_t)row * 512;
  float4 a = *(const float4*)&xr[lane * 8];
  float4 c = *(const float4*)&xr[lane * 8 + 4];
  float vv[8] = {a.x, a.y, a.z, a.w, c.x, c.y, c.z, c.w};
  float s = 0.f, q = 0.f;
#pragma unroll
  for (int j = 0; j < 8; ++j) { s += vv[j]; q += vv[j] * vv[j]; }
  for (int o = 32; o; o >>= 1) { s += __shfl_xor(s, o); q += __shfl_xor(q, o); }
  const float mean = s * (1.f / 512.f);
  const float var = q * (1.f / 512.f) - mean * mean;
  const float rstd = rsqrtf(var + 1e-3f);
  float4 g1 = *(const float4*)&g[lane * 8];
  float4 g2 = *(const float4*)&g[lane * 8 + 4];
  float4 b1 = *(const float4*)&bb[lane * 8];
  float4 b2 = *(const float4*)&bb[lane * 8 + 4];
  float gg[8] = {g1.x, g1.y, g1.z, g1.w, g2.x, g2.y, g2.z, g2.w};
  float bbv[8] = {b1.x, b1.y, b1.z, b1.w, b2.x, b2.y, b2.z, b2.w};
  bf16x8 ov;
#pragma unroll
  for (int j = 0; j < 8; ++j)
    ov[j] = (__bf16)((vv[j] - mean) * rstd * gg[j] + bbv[j]);
  *(bf16x8*)&h[(size_t)row * 512 + lane * 8] = ov;
}

// ---------------- FUSED qkv GEMM + attention, one block per (b,h) ----------------
// GEMM: A = h rows [b*96, b*96+96), B = head-grouped qkvT rows [h*192, h*192+192), K=512.
// Epilogue: K,Q (cols<128) -> LDS tiles; V (cols 128..191, waves wc=1 only) stays in acc
// registers until after softmax, then lands in vT over the dead sS region.
// Numerically identical to the previous separate qkv-gemm + attn (same MFMA k-order,
// same bf16 round points); pad rows 90..95 are finite and masked (w underflows to 0).
__global__ __launch_bounds__(256) void qkvattn_k(const __bf16* __restrict__ A,
                                                 const __bf16* __restrict__ BTh,
                                                 const float* __restrict__ bias,
                                                 float* __restrict__ x) {
  __shared__ __align__(16) char smem[64512];
  __bf16* kS = (__bf16*)smem;              // [96][72]  13824B
  __bf16* qS = (__bf16*)(smem + 13824);    // [96][72]  13824B
  __bf16* wS = (__bf16*)smem;              // [96][104] (aliases kS/qS after scores)
  float* sS = (float*)(smem + 27648);      // [96][96]  36864B
  __bf16* vT = (__bf16*)(smem + 27648);    // [64][104] (over dead sS, after softmax)
  __bf16* As = (__bf16*)(smem + 27648);            // [96][32]  6144B  (GEMM phase only)
  __bf16* Bs = (__bf16*)(smem + 27648 + 6144);     // [192][32] 12288B (GEMM phase only)

  const int tid = threadIdx.x;
  const int b = blockIdx.x >> 3, h = blockIdx.x & 7;
  const int wave = tid >> 6, lane = tid & 63, quad = lane >> 4, l16 = lane & 15;
  const int wr = wave & 1, wc = wave >> 1;
  const int lrow = lane >> 2, lkc = lane & 3;

  // ---- GEMM phase: acc[3][6] covers (wr*48..+48) x (wc*96..+96) of the 96x192 tile ----
  const __bf16* ga0 = A + (size_t)(b * 96 + wave * 16 + lrow) * 512 + lkc * 8;
  const __bf16* ga1 = A + (size_t)(b * 96 + ((wave & 1) + 4) * 16 + lrow) * 512 + lkc * 8;
  const __bf16* gbp[3];
#pragma unroll
  for (int t = 0; t < 3; ++t)
    gbp[t] = BTh + (size_t)(h * 192 + (wave + 4 * t) * 16 + lrow) * 512 + lkc * 8;

  f32x4 acc[3][6] = {};
  for (int kt = 0; kt < 16; ++kt) {
    const int kb = kt * 32;
    __syncthreads();
    gll16(ga0 + kb, &As[wave * 16 * 32]);
    if (wave < 2) gll16(ga1 + kb, &As[(wave + 4) * 16 * 32]);
#pragma unroll
    for (int t = 0; t < 3; ++t)
      gll16(gbp[t] + kb, &Bs[(wave + 4 * t) * 16 * 32]);
    __syncthreads();
    bf16x8 af[3], bq[6];
#pragma unroll
    for (int mt = 0; mt < 3; ++mt)
      af[mt] = *(const bf16x8*)&As[(wr * 48 + mt * 16 + l16) * 32 + quad * 8];
#pragma unroll
    for (int nt = 0; nt < 6; ++nt)
      bq[nt] = *(const bf16x8*)&Bs[(wc * 96 + nt * 16 + l16) * 32 + quad * 8];
#pragma unroll
    for (int mt = 0; mt < 3; ++mt)
#pragma unroll
      for (int nt = 0; nt < 6; ++nt)
        acc[mt][nt] = __builtin_amdgcn_mfma_f32_16x16x32_bf16(af[mt], bq[nt], acc[mt][nt], 0, 0, 0);
  }

  // epilogue: K,Q -> LDS (kS/qS disjoint from As/Bs, no barrier needed before writes)
#pragma unroll
  for (int nt = 0; nt < 6; ++nt) {
    const int col = wc * 96 + nt * 16 + l16;
    if (col < 128) {
      const float bvl = bias[h * 192 + col];
#pragma unroll
      for (int mt = 0; mt < 3; ++mt) {
#pragma unroll
        for (int r = 0; r < 4; ++r) {
          const int row = wr * 48 + mt * 16 + quad * 4 + r;
          const float v = acc[mt][nt][r] + bvl;
          if (col < 64) kS[row * 72 + col] = (__bf16)v;
          else qS[row * 72 + (col - 64)] = (__bf16)v;
        }
      }
    }
  }
  __syncthreads();

  // scores: s[i][j] = sum_d k[i,d] q[j,d] / 8, causal mask j<=i, j<90
  for (int tt = wave; tt < 36; tt += 4) {
    const int it = tt / 6, jt = tt - it * 6;
    f32x4 sacc = {0.f, 0.f, 0.f, 0.f};
#pragma unroll
    for (int ks = 0; ks < 2; ++ks) {
      bf16x8 af = *(const bf16x8*)&kS[(it * 16 + l16) * 72 + ks * 32 + quad * 8];
      bf16x8 bq = *(const bf16x8*)&qS[(jt * 16 + l16) * 72 + ks * 32 + quad * 8];
      sacc = __builtin_amdgcn_mfma_f32_16x16x32_bf16(af, bq, sacc, 0, 0, 0);
    }
    const int col = jt * 16 + l16;
#pragma unroll
    for (int r = 0; r < 4; ++r) {
      const int row = it * 16 + quad * 4 + r;
      sS[row * 96 + col] = (col <= row && col < 90) ? sacc[r] * 0.125f : -1e30f;
    }
  }
  __syncthreads();

  // row softmax -> wS (bf16)
  for (int row = wave; row < 96; row += 4) {
    const float e0 = sS[row * 96 + lane];
    const float e1 = (lane < 32) ? sS[row * 96 + 64 + lane] : -1e30f;
    float m = fmaxf(e0, e1);
    for (int o = 32; o; o >>= 1) m = fmaxf(m, __shfl_xor(m, o));
    const float p0 = __expf(e0 - m);
    const float p1 = (lane < 32) ? __expf(e1 - m) : 0.f;
    float s = p0 + p1;
    for (int o = 32; o; o >>= 1) s += __shfl_xor(s, o);
    const float inv = 1.f / s;
    wS[row * 104 + lane] = (__bf16)(p0 * inv);
    if (lane < 32) wS[row * 104 + 64 + lane] = (__bf16)(p1 * inv);
  }
  __syncthreads();

  // V epilogue: waves wc==1 hold V cols (128..191) in acc[.][2..5]; write transposed
  if (wc == 1) {
#pragma unroll
    for (int nt = 2; nt < 6; ++nt) {
      const int vd = nt * 16 + l16 - 32;  // 0..63
      const float bvl = bias[h * 192 + 128 + vd];
#pragma unroll
      for (int mt = 0; mt < 3; ++mt) {
#pragma unroll
        for (int r = 0; r < 4; ++r) {
          const int row = wr * 48 + mt * 16 + quad * 4 + r;
          vT[vd * 104 + row] = (__bf16)(acc[mt][nt][r] + bvl);
        }
      }
    }
  }
  __syncthreads();

  // PV: o[i][d] = sum_j w[i,j] v[j,d]; x[b*96 + i, h*64+d] += o
  for (int tt = wave; tt < 24; tt += 4) {
    const int it = tt >> 2, dt = tt & 3;
    f32x4 pacc = {0.f, 0.f, 0.f, 0.f};
#pragma unroll
    for (int ks = 0; ks < 3; ++ks) {
      bf16x8 aw = *(const bf16x8*)&wS[(it * 16 + l16) * 104 + ks * 32 + quad * 8];
      bf16x8 bv = *(const bf16x8*)&vT[(dt * 16 + l16) * 104 + ks * 32 + quad * 8];
      pacc = __builtin_amdgcn_mfma_f32_16x16x32_bf16(aw, bv, pacc, 0, 0, 0);
    }
    const int d = dt * 16 + l16;
#pragma unroll
    for (int r = 0; r < 4; ++r) {
      const int i = it * 16 + quad * 4 + r;
      if (i < 90) {
        float* p = x + (size_t)(b * 96 + i) * 512 + h * 64 + d;
        *p += pacc[r];
      }
    }
  }
}

// ---------------- fused final LN + head (state tokens only), 1 wave per output row ----------------
__global__ __launch_bounds__(64) void head_k(const float* __restrict__ x, const float* __restrict__ g,
                                             const float* __restrict__ bb, const float* __restrict__ whT,
                                             float* __restrict__ out) {
  const int m = blockIdx.x;  // 0..1919 = b*30+l
  const int b = m / 30, l = m - b * 30;
  const float* xr = x + (size_t)(b * 96 + 3 * l + 1) * 512;
  const int lane = threadIdx.x;
  float4 a = *(const float4*)&xr[lane * 8];
  float4 c = *(const float4*)&xr[lane * 8 + 4];
  float vv[8] = {a.x, a.y, a.z, a.w, c.x, c.y, c.z, c.w};
  float s = 0.f, q = 0.f;
#pragma unroll
  for (int j = 0; j < 8; ++j) { s += vv[j]; q += vv[j] * vv[j]; }
  for (int o = 32; o; o >>= 1) { s += __shfl_xor(s, o); q += __shfl_xor(q, o); }
  const float mean = s * (1.f / 512.f);
  const float var = q * (1.f / 512.f) - mean * mean;
  const float rstd = rsqrtf(var + 1e-3f);
  float4 g1 = *(const float4*)&g[lane * 8];
  float4 g2 = *(const float4*)&g[lane * 8 + 4];
  float4 b1 = *(const float4*)&bb[lane * 8];
  float4 b2 = *(const float4*)&bb[lane * 8 + 4];
  float gg[8] = {g1.x, g1.y, g1.z, g1.w, g2.x, g2.y, g2.z, g2.w};
  float bbv[8] = {b1.x, b1.y, b1.z, b1.w, b2.x, b2.y, b2.z, b2.w};
#pragma unroll
  for (int j = 0; j < 8; ++j)
    vv[j] = (vv[j] - mean) * rstd * gg[j] + bbv[j];
  for (int aa = 0; aa < 18; ++aa) {
    float4 w1v = *(const float4*)&whT[aa * 512 + lane * 8];
    float4 w2v = *(const float4*)&whT[aa * 512 + lane * 8 + 4];
    float ww[8] = {w1v.x, w1v.y, w1v.z, w1v.w, w2v.x, w2v.y, w2v.z, w2v.w};
    float d = 0.f;
#pragma unroll
    for (int j = 0; j < 8; ++j) d += vv[j] * ww[j];
    for (int o = 32; o; o >>= 1) d += __shfl_xor(d, o);
    if (lane == 0) out[m * 18 + aa] = d;
  }
}

// ---------------- host ----------------
extern "C" void kernel_launch(void* const* d_in, const int* in_sizes, int n_in,
                              void* d_out, int out_size, void* d_ws, size_t ws_size,
                              hipStream_t stream) {
  const float* rtgs = (const float*)d_in[0];
  const float* states = (const float*)d_in[1];
  const int* actions = (const int*)d_in[2];
  const int* timesteps = (const int*)d_in[3];
  const float* W_rtg = (const float*)d_in[4];
  const float* b_rtg = (const float*)d_in[5];
  const float* conv1_w = (const float*)d_in[6];
  const float* conv1_b = (const float*)d_in[7];
  const float* conv2_w = (const float*)d_in[8];
  const float* conv2_b = (const float*)d_in[9];
  const float* conv3_w = (const float*)d_in[10];
  const float* conv3_b = (const float*)d_in[11];
  const float* dense_s_w = (const float*)d_in[12];
  const float* dense_s_b = (const float*)d_in[13];
  const float* emb_a = (const float*)d_in[14];
  const float* abs_pos = (const float*)d_in[15];
  const float* rel_pos = (const float*)d_in[16];
  const float* ln1_g = (const float*)d_in[17];
  const float* ln1_b = (const float*)d_in[18];
  const float* Wk = (const float*)d_in[19];
  const float* bk = (const float*)d_in[20];
  const float* Wq = (const float*)d_in[21];
  const float* bq = (const float*)d_in[22];
  const float* Wv = (const float*)d_in[23];
  const float* bv = (const float*)d_in[24];
  const float* ln2_g = (const float*)d_in[25];
  const float* ln2_b = (const float*)d_in[26];
  const float* W1 = (const float*)d_in[27];
  const float* b1 = (const float*)d_in[28];
  const float* W2 = (const float*)d_in[29];
  const float* b2 = (const float*)d_in[30];
  const float* lnf_g = (const float*)d_in[31];
  const float* lnf_b = (const float*)d_in[32];
  const float* W_head = (const float*)d_in[33];
  float* out = (float*)d_out;

  // workspace layout (bytes); x/h use a 96-row stride per batch element (6144 rows total)
  char* W = (char*)d_ws;
  float* x = (float*)(W + 0);                   // 6144*512 f32      12,582,912
  __bf16* h = (__bf16*)(W + 12582912);          // 6144*512 bf16      6,291,456
  __bf16* qkvT = (__bf16*)(W + 18874368);       // 6*1536*512 bf16    9,437,184
  __bf16* w1T = (__bf16*)(W + 28311552);        // 6*2048*512 bf16   12,582,912
  __bf16* w2T = (__bf16*)(W + 40894464);        // 6*512*2048 bf16   12,582,912
  __bf16* dswT = (__bf16*)(W + 53477376);       // 512*3136 bf16      3,211,264
  __bf16* c1wT = (__bf16*)(W + 56688640);       // 128*256 bf16          65,536
  __bf16* c2wT = (__bf16*)(W + 56754176);       // 128*512 bf16         131,072
  __bf16* c3wT = (__bf16*)(W + 56885248);       // 128*576 bf16         147,456
  float* whT = (float*)(W + 57032704);          // 18*512 f32            36,864
  float* bqkv = (float*)(W + 57069568);         // 6*1536 f32            36,864
  // transient region base = 57,106,432
  __bf16* c1out = (__bf16*)(W + 57106432);      // 768000*32 bf16    49,152,000
  __bf16* c2out = (__bf16*)(W + 106258432);     // 155520*64 bf16    19,906,560
  __bf16* c3out = (__bf16*)(W + 57106432);      // 94080*64 bf16     (aliases dead c1out)
  float* ste = (float*)(W + 69148672);          // 1920*512 f32      (after c3out)
  __bf16* mlph = (__bf16*)(W + 57106432);       // 6144*2048 bf16    (aliases dead conv bufs)
  // end = 82,272,256 bytes

  const dim3 tb(32, 8);
  // weight transposes (BT layout) f32 -> bf16; conv1 weights absorb the /255
  transpose_pad<__bf16><<<dim3(8, 4, 1), tb, 0, stream>>>(conv1_w, c1wT, 256, 32, 128, 0, 0, 1.f / 255.f);
  transpose_pad<__bf16><<<dim3(16, 4, 1), tb, 0, stream>>>(conv2_w, c2wT, 512, 64, 128, 0, 0, 1.f);
  transpose_pad<__bf16><<<dim3(18, 4, 1), tb, 0, stream>>>(conv3_w, c3wT, 576, 64, 128, 0, 0, 1.f);
  transpose_pad<__bf16><<<dim3(98, 16, 1), tb, 0, stream>>>(dense_s_w, dswT, 3136, 512, 512, 0, 0, 1.f);
  transpose_qkv<<<dim3(16, 16, 18), tb, 0, stream>>>(Wk, Wq, Wv, qkvT);
  transpose_pad<__bf16><<<dim3(16, 64, 6), tb, 0, stream>>>(W1, w1T, 512, 2048, 2048, 512 * 2048, 2048 * 512, 1.f);
  transpose_pad<__bf16><<<dim3(64, 16, 6), tb, 0, stream>>>(W2, w2T, 2048, 512, 512, 2048 * 512, 512 * 2048, 1.f);
  transpose_pad<float><<<dim3(16, 1, 1), tb, 0, stream>>>(W_head, whT, 512, 18, 18, 0, 0, 1.f);
  biascat_k<<<6, 256, 0, stream>>>(bk, bq, bv, bqkv);

  // conv stem as implicit GEMM + dense embedding (all GEMMs: flat n-fastest grid, XCD-chunked)
  conv1_k<<<6000, 256, 0, stream>>>(states, c1wT, conv1_b, c1out);
  gemm_k<2, 128, 64, 2, 2, 512, ACT_RELU, OUT_BF16, 64, 1, 1><<<1215, 256, 0, stream>>>(c1out, c2wT, conv2_b, c2out);
  gemm_k<3, 128, 64, 2, 2, 576, ACT_RELU, OUT_BF16, 64, 1, 1><<<735, 256, 0, stream>>>(c2out, c3wT, conv3_b, c3out);
  gemm_k<0, 64, 64, 2, 2, 3136, ACT_TANH, OUT_F32, 512, 8, 1><<<240, 256, 0, stream>>>(c3out, dswT, dense_s_b, (void*)ste);

  embed_k<<<12288, 256, 0, stream>>>(rtgs, actions, timesteps, W_rtg, b_rtg, emb_a, abs_pos, rel_pos, ste, x);

  for (int i = 0; i < 6; ++i) {
    ln_k<<<1536, 256, 0, stream>>>(x, ln1_g + i * 512, ln1_b + i * 512, h);
    qkvattn_k<<<512, 256, 0, stream>>>(h, qkvT + (size_t)i * 1536 * 512, bqkv + i * 1536, x);
    ln_k<<<1536, 256, 0, stream>>>(x, ln2_g + i * 512, ln2_b + i * 512, h);
    gemm_k<0, 128, 128, 2, 2, 512, ACT_GELU, OUT_BF16, 2048, 16, 1><<<768, 256, 0, stream>>>(
        h, w1T + (size_t)i * 2048 * 512, b1 + i * 2048, mlph);
    gemm_k<0, 64, 64, 2, 2, 2048, ACT_NONE, OUT_ADD, 512, 8, 1><<<768, 256, 0, stream>>>(
        mlph, w2T + (size_t)i * 2048 * 512, b2 + i * 512, x);
  }

  head_k<<<1920, 64, 0, stream>>>(x, lnf_g, lnf_b, whT, out);
}

// Round 5
// 1291.554 us; speedup vs baseline: 1.0942x; 1.0019x over previous
//
#include <hip/hip_runtime.h>
#include <hip/hip_bf16.h>

typedef __attribute__((ext_vector_type(8))) __bf16 bf16x8;
typedef __attribute__((ext_vector_type(4))) float f32x4;

#define ACT_NONE 0
#define ACT_RELU 1
#define ACT_GELU 2
#define ACT_TANH 3
#define OUT_F32 0
#define OUT_BF16 1
#define OUT_ADD 2

// ---------------- async global->LDS, 16B per lane (lane writes lds_base + lane*16) ----------------
__device__ __forceinline__ void gll16(const void* g, void* l) {
  __builtin_amdgcn_global_load_lds(
      reinterpret_cast<const __attribute__((address_space(1))) unsigned int*>(
          reinterpret_cast<unsigned long long>(g)),
      reinterpret_cast<__attribute__((address_space(3))) unsigned int*>(
          reinterpret_cast<unsigned long long>(l)),
      16, 0, 0);
}

// ---------------- bijective XCD-chunked swizzle (m204): keep adjacent blocks on one XCD L2 ----------
__device__ __forceinline__ int xcd_swz(int bid, int n) {
  const int q = n >> 3, r = n & 7, x = bid & 7, o = bid >> 3;
  return (x < r ? x * (q + 1) : r * (q + 1) + (x - r) * q) + o;
}

// ---------------- implicit-GEMM A addressing ----------------
// MODE 0: plain row-major A[M][K]
// MODE 1: conv1 im2col: input (1920,84,84,4) f32, 8x8 s4 -> k=ky*32+(kx*4+ci)
// MODE 2: conv2 im2col: input (1920,20,20,32), 4x4 s2 -> k=(ky*4+kx)*32+ci
// MODE 3: conv3 im2col: input (1920,9,9,64),  3x3 s1 -> k=(ky*3+kx)*64+ci
template<int MODE, int K>
__device__ __forceinline__ size_t a_rowbase(int m) {
  if constexpr (MODE == 0) {
    return (size_t)m * K;
  } else if constexpr (MODE == 1) {
    int img = m / 400; int p = m - img * 400; int oy = p / 20; int ox = p - oy * 20;
    return (size_t)img * 28224 + oy * 1344 + ox * 16;
  } else if constexpr (MODE == 2) {
    int img = m / 81; int p = m - img * 81; int oy = p / 9; int ox = p - oy * 9;
    return (size_t)img * 12800 + oy * 1280 + ox * 64;
  } else {
    int img = m / 49; int p = m - img * 49; int oy = p / 7; int ox = p - oy * 7;
    return (size_t)img * 5184 + oy * 576 + ox * 64;
  }
}
// wave-uniform part of im2col k-offset (lane adds lkc*8 < 32; kb is a multiple of 32,
// and 32 divides every block stride, so the division never splits a 32-chunk)
template<int MODE>
__device__ __forceinline__ int f_koff(int kb) {
  if constexpr (MODE == 0) return kb;
  else if constexpr (MODE == 2) return (kb >> 7) * 640 + ((kb >> 5) & 3) * 32;
  else return kb + (kb / 192) * 384;  // MODE 3: ky*576 + (kb - ky*192)
}

__device__ __forceinline__ bf16x8 ld8f(const float* f) {
  float4 a = *(const float4*)f;
  float4 b = *(const float4*)(f + 4);
  bf16x8 r;
  r[0] = (__bf16)a.x; r[1] = (__bf16)a.y; r[2] = (__bf16)a.z; r[3] = (__bf16)a.w;
  r[4] = (__bf16)b.x; r[5] = (__bf16)b.y; r[6] = (__bf16)b.z; r[7] = (__bf16)b.w;
  return r;
}

__device__ __forceinline__ float act_apply(float v, int ACT) {
  if (ACT == ACT_RELU) return fmaxf(v, 0.f);
  if (ACT == ACT_GELU) return 0.5f * v * (1.f + erff(v * 0.70710678118f));
  if (ACT == ACT_TANH) return tanhf(v);
  return v;
}

// ---------------- generic MFMA GEMM:  C[M][N] = act(A * BT^T + bias) ----------------
// Flat 1-D n-fastest grid + XCD-chunked swizzle (r3-verified: A-panel L2 reuse).
template<int MODE, int TM, int TN, int WM, int WN, int K, int ACT, int OUTM, int LDC, int NBLK, int SWZ>
__global__ __launch_bounds__(256) void gemm_k(const __bf16* __restrict__ A,
                                              const __bf16* __restrict__ BT,
                                              const float* __restrict__ bias,
                                              void* __restrict__ C) {
  constexpr int SM = TM / WM, SN = TN / WN;
  constexpr int AM = SM / 16, AN = SN / 16;
  constexpr int TA = TM / 64, TB = TN / 64;  // wave-insts per wave for A / B staging
  __shared__ __align__(16) __bf16 As[TM * 32];
  __shared__ __align__(16) __bf16 Bs[TN * 32];
  const int tid = threadIdx.x;
  const int wave = tid >> 6, lane = tid & 63;
  const int quad = lane >> 4, l16 = lane & 15;
  const int wr = wave % WM, wc = wave / WM;
  const int bid = SWZ ? xcd_swz(blockIdx.x, gridDim.x) : blockIdx.x;
  const int bn = bid % NBLK, bm = bid / NBLK;
  const int m0 = bm * TM, n0 = bn * TN;
  const int lrow = lane >> 2, lkc = lane & 3;  // staging: lane -> (row, 8-elem chunk)

  const __bf16* ga[TA];
  const __bf16* gb[TB];
#pragma unroll
  for (int t = 0; t < TA; ++t)
    ga[t] = A + a_rowbase<MODE, K>(m0 + (wave + 4 * t) * 16 + lrow) + lkc * 8;
#pragma unroll
  for (int t = 0; t < TB; ++t)
    gb[t] = BT + (size_t)(n0 + (wave + 4 * t) * 16 + lrow) * K + lkc * 8;

  f32x4 acc[AM][AN] = {};
  for (int kt = 0; kt < K / 32; ++kt) {
    const int kb = kt * 32;
    const int fa = f_koff<MODE>(kb);
    __syncthreads();
#pragma unroll
    for (int t = 0; t < TA; ++t)
      gll16(ga[t] + fa, &As[(wave + 4 * t) * 16 * 32]);
#pragma unroll
    for (int t = 0; t < TB; ++t)
      gll16(gb[t] + kb, &Bs[(wave + 4 * t) * 16 * 32]);
    __syncthreads();
    bf16x8 af[AM], bf[AN];
#pragma unroll
    for (int mt = 0; mt < AM; ++mt)
      af[mt] = *(const bf16x8*)&As[(wr * SM + mt * 16 + l16) * 32 + quad * 8];
#pragma unroll
    for (int nt = 0; nt < AN; ++nt)
      bf[nt] = *(const bf16x8*)&Bs[(wc * SN + nt * 16 + l16) * 32 + quad * 8];
#pragma unroll
    for (int mt = 0; mt < AM; ++mt)
#pragma unroll
      for (int nt = 0; nt < AN; ++nt)
        acc[mt][nt] = __builtin_amdgcn_mfma_f32_16x16x32_bf16(af[mt], bf[nt], acc[mt][nt], 0, 0, 0);
  }

  // epilogue: C/D layout col=lane&15, row=quad*4+reg
#pragma unroll
  for (int nt = 0; nt < AN; ++nt) {
    const int col = n0 + wc * SN + nt * 16 + l16;
    const float bvl = bias[col];
#pragma unroll
    for (int mt = 0; mt < AM; ++mt) {
#pragma unroll
      for (int r = 0; r < 4; ++r) {
        const int row = m0 + wr * SM + mt * 16 + quad * 4 + r;
        float v = act_apply(acc[mt][nt][r] + bvl, ACT);
        const size_t off = (size_t)row * LDC + col;
        if constexpr (OUTM == OUT_F32) ((float*)C)[off] = v;
        else if constexpr (OUTM == OUT_BF16) ((__bf16*)C)[off] = (__bf16)v;
        else ((float*)C)[off] += v;
      }
    }
  }
}

// ---------------- conv1: f32 A (im2col MODE 1), 128x32 tile, K=256 ----------------
__global__ __launch_bounds__(256) void conv1_k(const float* __restrict__ A,
                                               const __bf16* __restrict__ BT,
                                               const float* __restrict__ bias,
                                               __bf16* __restrict__ C) {
  __shared__ __align__(16) __bf16 As[128 * 32];
  __shared__ __align__(16) __bf16 Bs[32 * 32];
  const int tid = threadIdx.x;
  const int wave = tid >> 6, lane = tid & 63;
  const int quad = lane >> 4, l16 = lane & 15;
  const int m0 = xcd_swz(blockIdx.x, gridDim.x) * 128;  // XCD-chunked: window overlap stays in L2
  const int lrow = lane >> 2, lkc = lane & 3;
  const int r0 = tid >> 2, k0o = (tid & 3) * 8;  // A staging: rows r0, r0+64
  const int r1 = r0 + 64;
  const size_t ar0 = a_rowbase<1, 256>(m0 + r0);
  const size_t ar1 = a_rowbase<1, 256>(m0 + r1);
  const __bf16* gB = BT + (size_t)(wave * 16 + lrow) * 256 + lkc * 8;  // used by waves 0,1

  f32x4 acc[2][2] = {};
  bf16x8 a0 = ld8f(A + ar0 + k0o);
  bf16x8 a1 = ld8f(A + ar1 + k0o);
  for (int kt = 0; kt < 8; ++kt) {
    const int kb = kt * 32;
    __syncthreads();
    if (wave < 2) gll16(gB + kb, &Bs[wave * 16 * 32]);
    *(bf16x8*)&As[r0 * 32 + k0o] = a0;
    *(bf16x8*)&As[r1 * 32 + k0o] = a1;
    __syncthreads();
    if (kt < 7) {
      const int fa = (kt + 1) * 336;  // f32 offset for k-block kt+1 (ky stride 336 floats)
      a0 = ld8f(A + ar0 + fa + k0o);
      a1 = ld8f(A + ar1 + fa + k0o);
    }
    bf16x8 af[2], bf[2];
#pragma unroll
    for (int mt = 0; mt < 2; ++mt)
      af[mt] = *(const bf16x8*)&As[(wave * 32 + mt * 16 + l16) * 32 + quad * 8];
#pragma unroll
    for (int nt = 0; nt < 2; ++nt)
      bf[nt] = *(const bf16x8*)&Bs[(nt * 16 + l16) * 32 + quad * 8];
#pragma unroll
    for (int mt = 0; mt < 2; ++mt)
#pragma unroll
      for (int nt = 0; nt < 2; ++nt)
        acc[mt][nt] = __builtin_amdgcn_mfma_f32_16x16x32_bf16(af[mt], bf[nt], acc[mt][nt], 0, 0, 0);
  }
#pragma unroll
  for (int nt = 0; nt < 2; ++nt) {
    const int col = nt * 16 + l16;
    const float bvl = bias[col];
#pragma unroll
    for (int mt = 0; mt < 2; ++mt) {
#pragma unroll
      for (int r = 0; r < 4; ++r) {
        const int row = m0 + wave * 32 + mt * 16 + quad * 4 + r;
        C[(size_t)row * 32 + col] = (__bf16)fmaxf(acc[mt][nt][r] + bvl, 0.f);
      }
    }
  }
}

// ---------------- unified prep: one 32x32 transpose tile (or biascat) per block ----------------
// mode 0: f32->bf16 transpose+pad, 1: f32->f32, 2: qkv head-grouped
__device__ __forceinline__ void tp32(const float* __restrict__ src, int R, int C, int Cpad,
                                     int bx, int by, float scale, int mode, int which,
                                     __bf16* dB, float* dF) {
  __shared__ float t[32][33];
  const int tx = threadIdx.x & 31, ty = threadIdx.x >> 5;
  const int r0 = bx * 32, c0 = by * 32;
  for (int i = ty; i < 32; i += 8) {
    int r = r0 + i, c = c0 + tx;
    t[i][tx] = (r < R && c < C) ? src[(size_t)r * C + c] : 0.f;
  }
  __syncthreads();
  for (int i = ty; i < 32; i += 8) {
    int c = c0 + i, r = r0 + tx;
    if (c < Cpad && r < R) {
      float v = (c < C) ? t[tx][i] * scale : 0.f;
      if (mode == 2) {
        const int row = ((c >> 6) * 192) + which * 64 + (c & 63);
        dB[(size_t)row * 512 + r] = (__bf16)v;
      } else if (mode == 1) {
        dF[(size_t)c * R + r] = v;
      } else {
        dB[(size_t)c * R + r] = (__bf16)v;
      }
    }
  }
}

__global__ __launch_bounds__(256) void prep_k(
    const float* c1w, const float* c2w, const float* c3w, const float* dsw,
    const float* Wk_, const float* Wq_, const float* Wv_,
    const float* W1_, const float* W2_, const float* Wh_,
    const float* bk_, const float* bq_, const float* bv_,
    __bf16* c1wT, __bf16* c2wT, __bf16* c3wT, __bf16* dswT, __bf16* qkvT,
    __bf16* w1T, __bf16* w2T, float* whT, float* bqkv) {
  int bid = blockIdx.x;
  if (bid < 32) { tp32(c1w, 256, 32, 128, bid & 7, bid >> 3, 1.f / 255.f, 0, 0, c1wT, nullptr); return; }
  bid -= 32;
  if (bid < 64) { tp32(c2w, 512, 64, 128, bid & 15, bid >> 4, 1.f, 0, 0, c2wT, nullptr); return; }
  bid -= 64;
  if (bid < 72) { tp32(c3w, 576, 64, 128, bid % 18, bid / 18, 1.f, 0, 0, c3wT, nullptr); return; }
  bid -= 72;
  if (bid < 1568) { tp32(dsw, 3136, 512, 512, bid % 98, bid / 98, 1.f, 0, 0, dswT, nullptr); return; }
  bid -= 1568;
  if (bid < 4608) {
    const int bx = bid & 15, by = (bid >> 4) & 15, z = bid >> 8;
    const int which = z / 6, i = z - which * 6;
    const float* s = (which == 0 ? Wk_ : which == 1 ? Wq_ : Wv_) + (size_t)i * 512 * 512;
    tp32(s, 512, 512, 512, bx, by, 1.f, 2, which, qkvT + (size_t)i * 1536 * 512, nullptr);
    return;
  }
  bid -= 4608;
  if (bid < 6144) {
    const int bx = bid & 15, by = (bid >> 4) & 63, z = bid >> 10;
    tp32(W1_ + (size_t)z * 512 * 2048, 512, 2048, 2048, bx, by, 1.f, 0, 0,
         w1T + (size_t)z * 2048 * 512, nullptr);
    return;
  }
  bid -= 6144;
  if (bid < 6144) {
    const int bx = bid & 63, by = (bid >> 6) & 15, z = bid >> 10;
    tp32(W2_ + (size_t)z * 2048 * 512, 2048, 512, 512, bx, by, 1.f, 0, 0,
         w2T + (size_t)z * 512 * 2048, nullptr);
    return;
  }
  bid -= 6144;
  if (bid < 16) { tp32(Wh_, 512, 18, 18, bid, 0, 1.f, 1, 0, nullptr, whT); return; }
  bid -= 16;
  // biascat: head-grouped, 6 blocks
  const int i = bid;
  for (int d = threadIdx.x; d < 512; d += 256) {
    const int g = (d >> 6) * 192 + (d & 63);
    bqkv[i * 1536 + g] = bk_[i * 512 + d];
    bqkv[i * 1536 + g + 64] = bq_[i * 512 + d];
    bqkv[i * 1536 + g + 128] = bv_[i * 512 + d];
  }
}

// ---------------- token embedding: x = interleave(rtg_e, st_e, a_e) + pos; 96-row stride/b ------
__global__ void embed_k(const float* __restrict__ rtgs, const int* __restrict__ actions,
                        const int* __restrict__ timesteps, const float* __restrict__ W_rtg,
                        const float* __restrict__ b_rtg, const float* __restrict__ emb_a,
                        const float* __restrict__ abs_pos, const float* __restrict__ rel_pos,
                        const float* __restrict__ ste, float* __restrict__ x) {
  const int idx = blockIdx.x * 256 + threadIdx.x;  // 64*96*512 total
  const int d = idx & 511; const int rb = idx >> 9;
  const int b = rb / 96, t = rb - b * 96;
  if (t >= 90) { x[idx] = 0.f; return; }  // pad rows: finite zeros (downstream-safe)
  const int l = t / 3, r = t - l * 3;
  const float pos = rel_pos[t * 512 + d] + abs_pos[(size_t)timesteps[b] * 512 + d];
  float tok;
  if (r == 0) tok = tanhf(rtgs[b * 30 + l] * W_rtg[d] + b_rtg[d]);
  else if (r == 1) tok = ste[(size_t)(b * 30 + l) * 512 + d];
  else tok = tanhf(emb_a[actions[b * 30 + l] * 512 + d]);
  x[idx] = tok + pos;
}

// ---------------- layernorm: h_bf16 = LN(x_f32) * g + b, one wave per row (ln2 only now) --------
__global__ __launch_bounds__(256) void ln_k(const float* __restrict__ x, const float* __restrict__ g,
                                            const float* __restrict__ bb, __bf16* __restrict__ h) {
  const int row = blockIdx.x * 4 + (threadIdx.x >> 6);
  const int lane = threadIdx.x & 63;
  const float* xr = x + (size_t)row * 512;
  float4 a = *(const float4*)&xr[lane * 8];
  float4 c = *(const float4*)&xr[lane * 8 + 4];
  float vv[8] = {a.x, a.y, a.z, a.w, c.x, c.y, c.z, c.w};
  float s = 0.f, q = 0.f;
#pragma unroll
  for (int j = 0; j < 8; ++j) { s += vv[j]; q += vv[j] * vv[j]; }
  for (int o = 32; o; o >>= 1) { s += __shfl_xor(s, o); q += __shfl_xor(q, o); }
  const float mean = s * (1.f / 512.f);
  const float var = q * (1.f / 512.f) - mean * mean;
  const float rstd = rsqrtf(var + 1e-3f);
  float4 g1 = *(const float4*)&g[lane * 8];
  float4 g2 = *(const float4*)&g[lane * 8 + 4];
  float4 b1 = *(const float4*)&bb[lane * 8];
  float4 b2 = *(const float4*)&bb[lane * 8 + 4];
  float gg[8] = {g1.x, g1.y, g1.z, g1.w, g2.x, g2.y, g2.z, g2.w};
  float bbv[8] = {b1.x, b1.y, b1.z, b1.w, b2.x, b2.y, b2.z, b2.w};
  bf16x8 ov;
#pragma unroll
  for (int j = 0; j < 8; ++j)
    ov[j] = (__bf16)((vv[j] - mean) * rstd * gg[j] + bbv[j]);
  *(bf16x8*)&h[(size_t)row * 512 + lane * 8] = ov;
}

__device__ __forceinline__ bf16x8 lnpack8(float4 a, float4 c, float mean, float rstd,
                                          const float* gS, const float* bS, int c0) {
  float4 g1 = *(const float4*)&gS[c0], g2 = *(const float4*)&gS[c0 + 4];
  float4 b1 = *(const float4*)&bS[c0], b2 = *(const float4*)&bS[c0 + 4];
  bf16x8 o;
  o[0] = (__bf16)((a.x - mean) * rstd * g1.x + b1.x);
  o[1] = (__bf16)((a.y - mean) * rstd * g1.y + b1.y);
  o[2] = (__bf16)((a.z - mean) * rstd * g1.z + b1.z);
  o[3] = (__bf16)((a.w - mean) * rstd * g1.w + b1.w);
  o[4] = (__bf16)((c.x - mean) * rstd * g2.x + b2.x);
  o[5] = (__bf16)((c.y - mean) * rstd * g2.y + b2.y);
  o[6] = (__bf16)((c.z - mean) * rstd * g2.z + b2.z);
  o[7] = (__bf16)((c.w - mean) * rstd * g2.w + b2.w);
  return o;
}

// ---------------- FUSED LN1 + qkv GEMM + attention, one block per (b,h) ----------------
// LN stats computed in-block (8x redundant across heads, overlapped); A staged from x (f32)
// with LN applied at the same bf16 rounding point ln_k used. XCD-swizzled so all 8 heads of
// a batch element share one XCD's L2 copy of its x-panel.
__global__ __launch_bounds__(256) void lnqkvattn_k(float* x,
                                                   const float* __restrict__ g,
                                                   const float* __restrict__ bb,
                                                   const __bf16* __restrict__ BTh,
                                                   const float* __restrict__ bias) {
  __shared__ __align__(16) char smem[64512];
  __bf16* kS = (__bf16*)smem;              // [96][72]  13824B
  __bf16* qS = (__bf16*)(smem + 13824);    // [96][72]  13824B
  __bf16* wS = (__bf16*)smem;              // [96][104] (aliases kS/qS after scores)
  float* sS = (float*)(smem + 27648);      // [96][96]  36864B (post-GEMM)
  __bf16* vT = (__bf16*)(smem + 27648);    // [64][104] (over dead sS, after softmax)
  __bf16* As = (__bf16*)(smem + 27648);            // [96][32]  6144B  (GEMM phase)
  __bf16* Bs = (__bf16*)(smem + 33792);            // [192][32] 12288B (GEMM phase)
  float* mS = (float*)(smem + 46080);              // mean[96] (GEMM phase)
  float* rS = (float*)(smem + 46464);              // rstd[96]
  float* gS = (float*)(smem + 46848);              // ln gamma[512]
  float* bS = (float*)(smem + 48896);              // ln beta[512]

  const int tid = threadIdx.x;
  const int bidw = xcd_swz(blockIdx.x, gridDim.x);
  const int b = bidw >> 3, h = bidw & 7;
  const int wave = tid >> 6, lane = tid & 63, quad = lane >> 4, l16 = lane & 15;
  const int wr = wave & 1, wc = wave >> 1;
  const int lrow = lane >> 2, lkc = lane & 3;
  const float* xb = x + (size_t)(b * 96) * 512;

  // phase 0: ln params to LDS + per-row stats (4 rows/wave in parallel, 16 lanes/row)
  for (int d = tid; d < 512; d += 256) { gS[d] = g[d]; bS[d] = bb[d]; }
  for (int rr = wave * 4 + quad; rr < 96; rr += 16) {
    const float* xr = xb + (size_t)rr * 512 + l16 * 32;
    float s = 0.f, q = 0.f;
#pragma unroll
    for (int j = 0; j < 8; ++j) {
      float4 v = *(const float4*)&xr[j * 4];
      s += v.x + v.y + v.z + v.w;
      q += v.x * v.x + v.y * v.y + v.z * v.z + v.w * v.w;
    }
#pragma unroll
    for (int o = 8; o; o >>= 1) { s += __shfl_xor(s, o, 16); q += __shfl_xor(q, o, 16); }
    if (l16 == 0) {
      const float mean = s * (1.f / 512.f);
      const float var = q * (1.f / 512.f) - mean * mean;
      mS[rr] = mean;
      rS[rr] = rsqrtf(var + 1e-3f);
    }
  }
  __syncthreads();

  // ---- GEMM phase: acc[3][6] covers (wr*48..+48) x (wc*96..+96) of the 96x192 tile ----
  const __bf16* gbp[3];
#pragma unroll
  for (int t = 0; t < 3; ++t)
    gbp[t] = BTh + (size_t)(h * 192 + (wave + 4 * t) * 16 + lrow) * 512 + lkc * 8;

  const int ur = tid >> 2, uc = (tid & 3) * 8;  // A staging unit: rows ur, ur+64
  const float mv0 = mS[ur], rv0 = rS[ur];
  float mv1 = 0.f, rv1 = 0.f;
  if (tid < 128) { mv1 = mS[ur + 64]; rv1 = rS[ur + 64]; }
  float4 p0a = *(const float4*)&xb[(size_t)ur * 512 + uc];
  float4 p0b = *(const float4*)&xb[(size_t)ur * 512 + uc + 4];
  float4 p1a = {0.f, 0.f, 0.f, 0.f}, p1b = {0.f, 0.f, 0.f, 0.f};
  if (tid < 128) {
    p1a = *(const float4*)&xb[(size_t)(ur + 64) * 512 + uc];
    p1b = *(const float4*)&xb[(size_t)(ur + 64) * 512 + uc + 4];
  }

  f32x4 acc[3][6] = {};
  for (int kt = 0; kt < 16; ++kt) {
    const int kb = kt * 32;
    __syncthreads();
#pragma unroll
    for (int t = 0; t < 3; ++t)
      gll16(gbp[t] + kb, &Bs[(wave + 4 * t) * 16 * 32]);
    *(bf16x8*)&As[ur * 32 + uc] = lnpack8(p0a, p0b, mv0, rv0, gS, bS, kb + uc);
    if (tid < 128)
      *(bf16x8*)&As[(ur + 64) * 32 + uc] = lnpack8(p1a, p1b, mv1, rv1, gS, bS, kb + uc);
    __syncthreads();
    if (kt < 15) {
      const int nb = kb + 32 + uc;
      p0a = *(const float4*)&xb[(size_t)ur * 512 + nb];
      p0b = *(const float4*)&xb[(size_t)ur * 512 + nb + 4];
      if (tid < 128) {
        p1a = *(const float4*)&xb[(size_t)(ur + 64) * 512 + nb];
        p1b = *(const float4*)&xb[(size_t)(ur + 64) * 512 + nb + 4];
      }
    }
    bf16x8 af[3], bq[6];
#pragma unroll
    for (int mt = 0; mt < 3; ++mt)
      af[mt] = *(const bf16x8*)&As[(wr * 48 + mt * 16 + l16) * 32 + quad * 8];
#pragma unroll
    for (int nt = 0; nt < 6; ++nt)
      bq[nt] = *(const bf16x8*)&Bs[(wc * 96 + nt * 16 + l16) * 32 + quad * 8];
#pragma unroll
    for (int mt = 0; mt < 3; ++mt)
#pragma unroll
      for (int nt = 0; nt < 6; ++nt)
        acc[mt][nt] = __builtin_amdgcn_mfma_f32_16x16x32_bf16(af[mt], bq[nt], acc[mt][nt], 0, 0, 0);
  }

  // epilogue: K,Q -> LDS (kS/qS disjoint from As/Bs)
#pragma unroll
  for (int nt = 0; nt < 6; ++nt) {
    const int col = wc * 96 + nt * 16 + l16;
    if (col < 128) {
      const float bvl = bias[h * 192 + col];
#pragma unroll
      for (int mt = 0; mt < 3; ++mt) {
#pragma unroll
        for (int r = 0; r < 4; ++r) {
          const int row = wr * 48 + mt * 16 + quad * 4 + r;
          const float v = acc[mt][nt][r] + bvl;
          if (col < 64) kS[row * 72 + col] = (__bf16)v;
          else qS[row * 72 + (col - 64)] = (__bf16)v;
        }
      }
    }
  }
  __syncthreads();

  // scores: s[i][j] = sum_d k[i,d] q[j,d] / 8, causal mask j<=i, j<90
  for (int tt = wave; tt < 36; tt += 4) {
    const int it = tt / 6, jt = tt - it * 6;
    f32x4 sacc = {0.f, 0.f, 0.f, 0.f};
#pragma unroll
    for (int ks = 0; ks < 2; ++ks) {
      bf16x8 af = *(const bf16x8*)&kS[(it * 16 + l16) * 72 + ks * 32 + quad * 8];
      bf16x8 bq = *(const bf16x8*)&qS[(jt * 16 + l16) * 72 + ks * 32 + quad * 8];
      sacc = __builtin_amdgcn_mfma_f32_16x16x32_bf16(af, bq, sacc, 0, 0, 0);
    }
    const int col = jt * 16 + l16;
#pragma unroll
    for (int r = 0; r < 4; ++r) {
      const int row = it * 16 + quad * 4 + r;
      sS[row * 96 + col] = (col <= row && col < 90) ? sacc[r] * 0.125f : -1e30f;
    }
  }
  __syncthreads();

  // row softmax -> wS (bf16)
  for (int row = wave; row < 96; row += 4) {
    const float e0 = sS[row * 96 + lane];
    const float e1 = (lane < 32) ? sS[row * 96 + 64 + lane] : -1e30f;
    float m = fmaxf(e0, e1);
    for (int o = 32; o; o >>= 1) m = fmaxf(m, __shfl_xor(m, o));
    const float p0 = __expf(e0 - m);
    const float p1 = (lane < 32) ? __expf(e1 - m) : 0.f;
    float s = p0 + p1;
    for (int o = 32; o; o >>= 1) s += __shfl_xor(s, o);
    const float inv = 1.f / s;
    wS[row * 104 + lane] = (__bf16)(p0 * inv);
    if (lane < 32) wS[row * 104 + 64 + lane] = (__bf16)(p1 * inv);
  }
  __syncthreads();

  // V epilogue: waves wc==1 hold V cols (128..191) in acc[.][2..5]; write transposed
  if (wc == 1) {
#pragma unroll
    for (int nt = 2; nt < 6; ++nt) {
      const int vd = nt * 16 + l16 - 32;  // 0..63
      const float bvl = bias[h * 192 + 128 + vd];
#pragma unroll
      for (int mt = 0; mt < 3; ++mt) {
#pragma unroll
        for (int r = 0; r < 4; ++r) {
          const int row = wr * 48 + mt * 16 + quad * 4 + r;
          vT[vd * 104 + row] = (__bf16)(acc[mt][nt][r] + bvl);
        }
      }
    }
  }
  __syncthreads();

  // PV: o[i][d] = sum_j w[i,j] v[j,d]; x[b*96 + i, h*64+d] += o
  for (int tt = wave; tt < 24; tt += 4) {
    const int it = tt >> 2, dt = tt & 3;
    f32x4 pacc = {0.f, 0.f, 0.f, 0.f};
#pragma unroll
    for (int ks = 0; ks < 3; ++ks) {
      bf16x8 aw = *(const bf16x8*)&wS[(it * 16 + l16) * 104 + ks * 32 + quad * 8];
      bf16x8 bv = *(const bf16x8*)&vT[(dt * 16 + l16) * 104 + ks * 32 + quad * 8];
      pacc = __builtin_amdgcn_mfma_f32_16x16x32_bf16(aw, bv, pacc, 0, 0, 0);
    }
    const int d = dt * 16 + l16;
#pragma unroll
    for (int r = 0; r < 4; ++r) {
      const int i = it * 16 + quad * 4 + r;
      if (i < 90) {
        float* p = x + (size_t)(b * 96 + i) * 512 + h * 64 + d;
        *p += pacc[r];
      }
    }
  }
}

// ---------------- fused final LN + head (state tokens only), 1 wave per output row ----------------
__global__ __launch_bounds__(64) void head_k(const float* __restrict__ x, const float* __restrict__ g,
                                             const float* __restrict__ bb, const float* __restrict__ whT,
                                             float* __restrict__ out) {
  const int m = blockIdx.x;  // 0..1919 = b*30+l
  const int b = m / 30, l = m - b * 30;
  const float* xr = x + (size_t)(b * 96 + 3 * l + 1) * 512;
  const int lane = threadIdx.x;
  float4 a = *(const float4*)&xr[lane * 8];
  float4 c = *(const float4*)&xr[lane * 8 + 4];
  float vv[8] = {a.x, a.y, a.z, a.w, c.x, c.y, c.z, c.w};
  float s = 0.f, q = 0.f;
#pragma unroll
  for (int j = 0; j < 8; ++j) { s += vv[j]; q += vv[j] * vv[j]; }
  for (int o = 32; o; o >>= 1) { s += __shfl_xor(s, o); q += __shfl_xor(q, o); }
  const float mean = s * (1.f / 512.f);
  const float var = q * (1.f / 512.f) - mean * mean;
  const float rstd = rsqrtf(var + 1e-3f);
  float4 g1 = *(const float4*)&g[lane * 8];
  float4 g2 = *(const float4*)&g[lane * 8 + 4];
  float4 b1 = *(const float4*)&bb[lane * 8];
  float4 b2 = *(const float4*)&bb[lane * 8 + 4];
  float gg[8] = {g1.x, g1.y, g1.z, g1.w, g2.x, g2.y, g2.z, g2.w};
  float bbv[8] = {b1.x, b1.y, b1.z, b1.w, b2.x, b2.y, b2.z, b2.w};
#pragma unroll
  for (int j = 0; j < 8; ++j)
    vv[j] = (vv[j] - mean) * rstd * gg[j] + bbv[j];
  for (int aa = 0; aa < 18; ++aa) {
    float4 w1v = *(const float4*)&whT[aa * 512 + lane * 8];
    float4 w2v = *(const float4*)&whT[aa * 512 + lane * 8 + 4];
    float ww[8] = {w1v.x, w1v.y, w1v.z, w1v.w, w2v.x, w2v.y, w2v.z, w2v.w};
    float d = 0.f;
#pragma unroll
    for (int j = 0; j < 8; ++j) d += vv[j] * ww[j];
    for (int o = 32; o; o >>= 1) d += __shfl_xor(d, o);
    if (lane == 0) out[m * 18 + aa] = d;
  }
}

// ---------------- host ----------------
extern "C" void kernel_launch(void* const* d_in, const int* in_sizes, int n_in,
                              void* d_out, int out_size, void* d_ws, size_t ws_size,
                              hipStream_t stream) {
  const float* rtgs = (const float*)d_in[0];
  const float* states = (const float*)d_in[1];
  const int* actions = (const int*)d_in[2];
  const int* timesteps = (const int*)d_in[3];
  const float* W_rtg = (const float*)d_in[4];
  const float* b_rtg = (const float*)d_in[5];
  const float* conv1_w = (const float*)d_in[6];
  const float* conv1_b = (const float*)d_in[7];
  const float* conv2_w = (const float*)d_in[8];
  const float* conv2_b = (const float*)d_in[9];
  const float* conv3_w = (const float*)d_in[10];
  const float* conv3_b = (const float*)d_in[11];
  const float* dense_s_w = (const float*)d_in[12];
  const float* dense_s_b = (const float*)d_in[13];
  const float* emb_a = (const float*)d_in[14];
  const float* abs_pos = (const float*)d_in[15];
  const float* rel_pos = (const float*)d_in[16];
  const float* ln1_g = (const float*)d_in[17];
  const float* ln1_b = (const float*)d_in[18];
  const float* Wk = (const float*)d_in[19];
  const float* bk = (const float*)d_in[20];
  const float* Wq = (const float*)d_in[21];
  const float* bq = (const float*)d_in[22];
  const float* Wv = (const float*)d_in[23];
  const float* bv = (const float*)d_in[24];
  const float* ln2_g = (const float*)d_in[25];
  const float* ln2_b = (const float*)d_in[26];
  const float* W1 = (const float*)d_in[27];
  const float* b1 = (const float*)d_in[28];
  const float* W2 = (const float*)d_in[29];
  const float* b2 = (const float*)d_in[30];
  const float* lnf_g = (const float*)d_in[31];
  const float* lnf_b = (const float*)d_in[32];
  const float* W_head = (const float*)d_in[33];
  float* out = (float*)d_out;

  // workspace layout (bytes); x/h use a 96-row stride per batch element (6144 rows total)
  char* W = (char*)d_ws;
  float* x = (float*)(W + 0);                   // 6144*512 f32      12,582,912
  __bf16* h = (__bf16*)(W + 12582912);          // 6144*512 bf16      6,291,456
  __bf16* qkvT = (__bf16*)(W + 18874368);       // 6*1536*512 bf16    9,437,184
  __bf16* w1T = (__bf16*)(W + 28311552);        // 6*2048*512 bf16   12,582,912
  __bf16* w2T = (__bf16*)(W + 40894464);        // 6*512*2048 bf16   12,582,912
  __bf16* dswT = (__bf16*)(W + 53477376);       // 512*3136 bf16      3,211,264
  __bf16* c1wT = (__bf16*)(W + 56688640);       // 128*256 bf16          65,536
  __bf16* c2wT = (__bf16*)(W + 56754176);       // 128*512 bf16         131,072
  __bf16* c3wT = (__bf16*)(W + 56885248);       // 128*576 bf16         147,456
  float* whT = (float*)(W + 57032704);          // 18*512 f32            36,864
  float* bqkv = (float*)(W + 57069568);         // 6*1536 f32            36,864
  // transient region base = 57,106,432
  __bf16* c1out = (__bf16*)(W + 57106432);      // 768000*32 bf16    49,152,000
  __bf16* c2out = (__bf16*)(W + 106258432);     // 155520*64 bf16    19,906,560
  __bf16* c3out = (__bf16*)(W + 57106432);      // 94080*64 bf16     (aliases dead c1out)
  float* ste = (float*)(W + 69148672);          // 1920*512 f32      (after c3out)
  __bf16* mlph = (__bf16*)(W + 57106432);       // 6144*2048 bf16    (aliases dead conv bufs)
  // end = 82,272,256 bytes

  // all weight prep in ONE launch (8 transposes + biascat job table)
  prep_k<<<18654, 256, 0, stream>>>(conv1_w, conv2_w, conv3_w, dense_s_w, Wk, Wq, Wv,
                                    W1, W2, W_head, bk, bq, bv,
                                    c1wT, c2wT, c3wT, dswT, qkvT, w1T, w2T, whT, bqkv);

  // conv stem as implicit GEMM + dense embedding (all GEMMs: flat n-fastest grid, XCD-chunked)
  conv1_k<<<6000, 256, 0, stream>>>(states, c1wT, conv1_b, c1out);
  gemm_k<2, 128, 64, 2, 2, 512, ACT_RELU, OUT_BF16, 64, 1, 1><<<1215, 256, 0, stream>>>(c1out, c2wT, conv2_b, c2out);
  gemm_k<3, 128, 64, 2, 2, 576, ACT_RELU, OUT_BF16, 64, 1, 1><<<735, 256, 0, stream>>>(c2out, c3wT, conv3_b, c3out);
  gemm_k<0, 64, 64, 2, 2, 3136, ACT_TANH, OUT_F32, 512, 8, 1><<<240, 256, 0, stream>>>(c3out, dswT, dense_s_b, (void*)ste);

  embed_k<<<12288, 256, 0, stream>>>(rtgs, actions, timesteps, W_rtg, b_rtg, emb_a, abs_pos, rel_pos, ste, x);

  for (int i = 0; i < 6; ++i) {
    lnqkvattn_k<<<512, 256, 0, stream>>>(x, ln1_g + i * 512, ln1_b + i * 512,
                                         qkvT + (size_t)i * 1536 * 512, bqkv + i * 1536);
    ln_k<<<1536, 256, 0, stream>>>(x, ln2_g + i * 512, ln2_b + i * 512, h);
    gemm_k<0, 128, 128, 2, 2, 512, ACT_GELU, OUT_BF16, 2048, 16, 1><<<768, 256, 0, stream>>>(
        h, w1T + (size_t)i * 2048 * 512, b1 + i * 2048, mlph);
    gemm_k<0, 64, 64, 2, 2, 2048, ACT_NONE, OUT_ADD, 512, 8, 1><<<768, 256, 0, stream>>>(
        mlph, w2T + (size_t)i * 2048 * 512, b2 + i * 512, x);
  }

  head_k<<<1920, 64, 0, stream>>>(x, lnf_g, lnf_b, whT, out);
}